// Round 8
// baseline (562.167 us; speedup 1.0000x reference)
//
#include <hip/hip_runtime.h>
#include <hip/hip_bf16.h>
#include <math.h>

#define DEVFN __device__ __forceinline__

typedef unsigned int uint32;
typedef unsigned short ushort_t;

using bf16x8 = __attribute__((ext_vector_type(8))) short;
using f32x4  = __attribute__((ext_vector_type(4))) float;
using f32x2  = __attribute__((ext_vector_type(2))) float;

DEVFN float bf2f(ushort_t u) {
    union { uint32 i; float f; } v; v.i = ((uint32)u) << 16; return v.f;
}
DEVFN float asf(uint32 u) {
    union { uint32 i; float f; } v; v.i = u; return v.f;
}
DEVFN ushort_t f2bf(float f) {
    union { float f; uint32 i; } v; v.f = f;
    uint32 u = v.i;
    uint32 r = (u + 0x7FFFu + ((u >> 16) & 1u)) >> 16;
    return (ushort_t)r;
}

DEVFN void gload_lds16(const void* g, void* l) {
    __builtin_amdgcn_global_load_lds(
        (const __attribute__((address_space(1))) void*)g,
        (__attribute__((address_space(3))) void*)l, 16, 0, 0);
}

// ---------- casts ----------
__global__ void k_cast_x(const float* __restrict__ x, ushort_t* __restrict__ xb, int N) {
    int total = N * 128;
    for (int i = blockIdx.x * blockDim.x + threadIdx.x; i < total; i += gridDim.x * blockDim.x) {
        int col = i & 127, row = i >> 7;
        float v = (col < 100) ? x[row * 100 + col] : 0.f;
        xb[i] = f2bf(v);
    }
}

DEVFN void cast_one(const float* __restrict__ w, ushort_t* __restrict__ wt,
                    int j, int K, int Nout, int Kp) {
    int k = j % Kp, n = j / Kp;
    float v = (k < K && n < Nout) ? w[k * Nout + n] : 0.f;
    wt[j] = f2bf(v);
}

// all 6 weight transposes in one kernel (fixed sizes)
__global__ void k_cast_wall(const float* __restrict__ wl0, const float* __restrict__ wr0,
                            const float* __restrict__ wl1, const float* __restrict__ wr1,
                            const float* __restrict__ wl2, const float* __restrict__ wr2,
                            ushort_t* __restrict__ wlt0, ushort_t* __restrict__ wrt0,
                            ushort_t* __restrict__ wlt1, ushort_t* __restrict__ wrt1,
                            ushort_t* __restrict__ wcat2) {
    const int total = 229376;
    for (int i = blockIdx.x * blockDim.x + threadIdx.x; i < total; i += gridDim.x * blockDim.x) {
        int j = i;
        if (j < 32768)        cast_one(wl0, wlt0, j, 100, 256, 128);
        else if (j < 65536)   cast_one(wr0, wrt0, j - 32768, 100, 256, 128);
        else if (j < 131072)  cast_one(wl1, wlt1, j - 65536, 256, 256, 256);
        else if (j < 196608)  cast_one(wr1, wrt1, j - 131072, 256, 256, 256);
        else if (j < 212992)  cast_one(wl2, wcat2, j - 196608, 256, 47, 256);
        else                  cast_one(wr2, wcat2 + 16384, j - 212992, 256, 47, 256);
    }
}

// ---------- CSR build: binned counting sort by dst>>10, PADDED to 16 ----------
__global__ void k_bincount(const int* __restrict__ dst, int E, int CH, int nbins, int nblk,
                           int* __restrict__ binCnt) {
    __shared__ int scnt[128];
    int blk = blockIdx.x, tid = threadIdx.x;
    for (int b = tid; b < 128; b += 256) scnt[b] = 0;
    __syncthreads();
    int e0 = blk * CH, e1 = min(E, e0 + CH);
    for (int i = e0 + tid; i < e1; i += 256)
        atomicAdd(&scnt[dst[i] >> 10], 1);
    __syncthreads();
    for (int b = tid; b < nbins; b += 256) binCnt[b * nblk + blk] = scnt[b];
}

__global__ void k_blocksum(const int* __restrict__ v, int n, int* __restrict__ bsum) {
    __shared__ int s[1024];
    int i = blockIdx.x * 1024 + threadIdx.x;
    s[threadIdx.x] = (i < n) ? v[i] : 0;
    __syncthreads();
    for (int o = 512; o > 0; o >>= 1) {
        if (threadIdx.x < o) s[threadIdx.x] += s[threadIdx.x + o];
        __syncthreads();
    }
    if (threadIdx.x == 0) bsum[blockIdx.x] = s[0];
}

__global__ void k_scanb(int* __restrict__ bsum, int NB) {
    if (blockIdx.x == 0 && threadIdx.x == 0) {
        int acc = 0;
        for (int i = 0; i < NB; ++i) { int v = bsum[i]; bsum[i] = acc; acc += v; }
    }
}

__global__ void k_exscan(const int* __restrict__ v, const int* __restrict__ bsum,
                         int n, int* __restrict__ outOff) {
    __shared__ int s[1024];
    int t = threadIdx.x;
    int i = blockIdx.x * 1024 + t;
    int val = (i < n) ? v[i] : 0;
    s[t] = val;
    __syncthreads();
    for (int o = 1; o < 1024; o <<= 1) {
        int add = (t >= o) ? s[t - o] : 0;
        __syncthreads();
        s[t] += add;
        __syncthreads();
    }
    if (i < n) outOff[i] = s[t] - val + bsum[blockIdx.x];
}

__global__ void k_binscatter(const int* __restrict__ src, const int* __restrict__ dst,
                             int E, int CH, int nbins, int nblk,
                             const int* __restrict__ binOff, int* __restrict__ ebin) {
    __shared__ int scur[128];
    int blk = blockIdx.x, tid = threadIdx.x;
    for (int b = tid; b < nbins; b += 256) scur[b] = binOff[b * nblk + blk];
    __syncthreads();
    int e0 = blk * CH, e1 = min(E, e0 + CH);
    for (int i = e0 + tid; i < e1; i += 256) {
        int d = dst[i];
        int b = d >> 10;
        int pos = atomicAdd(&scur[b], 1);
        ebin[pos] = (src[i] << 10) | (d & 1023);
    }
}

// Per-bin CSR finalize with per-node padding to multiple of 16.
// Pad entries point to node N (a zeroed feature row). Per-bin padded base:
// pbase = align16(binStart) + bin*15376 (>= sum of previous bins' padded sizes).
__global__ void k_bincsr(const int* __restrict__ ebin, const int* __restrict__ binOff,
                         int E, int N, int nbins, int nblk,
                         int* __restrict__ poffs, int* __restrict__ deg, int* __restrict__ csr2) {
    __shared__ int sdeg[1024];
    __shared__ int scur[1024];
    int bin = blockIdx.x, t = threadIdx.x;
    int binStart = binOff[bin * nblk];
    int binEnd = (bin + 1 < nbins) ? binOff[(bin + 1) * nblk] : E;
    int pbase = ((binStart + 15) & ~15) + bin * 15376;
    sdeg[t] = 0;
    __syncthreads();
    for (int i = binStart + t; i < binEnd; i += 1024)
        atomicAdd(&sdeg[ebin[i] & 1023], 1);
    __syncthreads();
    int v = sdeg[t];
    int pv = (v + 15) & ~15;
    sdeg[t] = pv;
    __syncthreads();
    for (int o = 1; o < 1024; o <<= 1) {
        int add = (t >= o) ? sdeg[t - o] : 0;
        __syncthreads();
        sdeg[t] += add;
        __syncthreads();
    }
    int pex = sdeg[t] - pv;
    int node = bin * 1024 + t;
    if (node < N) { poffs[node] = pbase + pex; deg[node] = v; }
    scur[t] = pex;
    __syncthreads();
    for (int i = binStart + t; i < binEnd; i += 1024) {
        int e = ebin[i];
        int slot = atomicAdd(&scur[e & 1023], 1);
        csr2[pbase + slot] = e >> 10;
    }
    for (int j = v; j < pv; ++j) csr2[pbase + pex + j] = N;  // padding -> zero row
}

// ---------- aggregation: wave per node, padded edge lists, no masks ----------
// Row = D*2 B = LPR lanes x 16 B; EPG = 64/LPR edges per gather instruction.
// 4 gathers in flight (int4 index load, sub-major edge assignment).
template <int D>
__global__ __launch_bounds__(256) void k_agg(
    const ushort_t* __restrict__ h, const int* __restrict__ poffs,
    const int* __restrict__ deg, const int* __restrict__ csr2,
    int N, ushort_t* __restrict__ mean) {
    constexpr int LPR = D / 8;        // lanes per row
    constexpr int EPG = 64 / LPR;     // edges per gather (2 for D=256, 4 for D=128)
    constexpr int STEP = 4 * EPG;     // edges per iteration
    int wid = (blockIdx.x * blockDim.x + threadIdx.x) >> 6;
    int lane = threadIdx.x & 63;
    if (wid >= N) return;
    const int seg = lane % LPR, sub = lane / LPR;
    int off = poffs[wid], cnt = deg[wid];
    int pcnt = (cnt + 15) & ~15;
    f32x2 acc[4] = {};
    const ushort_t* hp = h + seg * 8;
    int4 idx = *(const int4*)(csr2 + off + sub * 4);
    for (int b = 0; b < pcnt; b += STEP) {
        uint4 d0 = *(const uint4*)(hp + (size_t)idx.x * D);
        uint4 d1 = *(const uint4*)(hp + (size_t)idx.y * D);
        uint4 d2 = *(const uint4*)(hp + (size_t)idx.z * D);
        uint4 d3 = *(const uint4*)(hp + (size_t)idx.w * D);
        int4 idxn = *(const int4*)(csr2 + off + b + STEP + sub * 4);
        uint32 dd[16] = {d0.x, d0.y, d0.z, d0.w, d1.x, d1.y, d1.z, d1.w,
                         d2.x, d2.y, d2.z, d2.w, d3.x, d3.y, d3.z, d3.w};
#pragma unroll
        for (int q = 0; q < 16; ++q) {
            f32x2 tv;
            tv.x = asf(dd[q] << 16);
            tv.y = asf(dd[q] & 0xffff0000u);
            acc[q & 3] += tv;
        }
        idx = idxn;
    }
    float a[8] = {acc[0].x, acc[0].y, acc[1].x, acc[1].y,
                  acc[2].x, acc[2].y, acc[3].x, acc[3].y};
#pragma unroll
    for (int o = LPR; o < 64; o <<= 1) {
#pragma unroll
        for (int k = 0; k < 8; ++k) a[k] += __shfl_xor(a[k], o);
    }
    if (sub == 0) {
        float inv = 1.f / fmaxf((float)cnt, 1.f);
        uint4 o4;
        o4.x = (uint32)f2bf(a[0] * inv) | ((uint32)f2bf(a[1] * inv) << 16);
        o4.y = (uint32)f2bf(a[2] * inv) | ((uint32)f2bf(a[3] * inv) << 16);
        o4.z = (uint32)f2bf(a[4] * inv) | ((uint32)f2bf(a[5] * inv) << 16);
        o4.w = (uint32)f2bf(a[6] * inv) | ((uint32)f2bf(a[7] * inv) << 16);
        *(uint4*)(mean + (size_t)wid * D + seg * 8) = o4;
    }
}

// ---------- MFMA GEMM: 128-row tile x ALL output cols (single col-block) ----------
// MODE 0: out = A1@B1^T + A2@B2^T, bf16 [M][256], fused BN column sum/sumsq.
// MODE 1: out = A1@B1^T; cols 0..63 -> bf16 t2 [M][64], 64..127 -> f32 r2 [M][64] (+bias).
template <int BN, int WROWS, int WCOLS, int MODE>
__global__ __launch_bounds__(512) void k_gemm(
    const ushort_t* __restrict__ A1, const ushort_t* __restrict__ B1,
    const ushort_t* __restrict__ A2, const ushort_t* __restrict__ B2,
    int KP, const float* __restrict__ bias,
    ushort_t* __restrict__ out_bf, float* __restrict__ out_f,
    float* __restrict__ stats, int M) {
    constexpr int BM = 128, BK = 64;
    constexpr int WM = BM / WROWS, WN = BN / WCOLS;
    constexpr int M_REP = WM / 16, N_REP = WN / 16;
    constexpr int SIDES = (MODE == 0) ? 2 : 1;
    __shared__ ushort_t Alds[BM * BK];
    __shared__ ushort_t Blds[BN * BK];
    __shared__ float sstat[2][BN];
    const int tid = threadIdx.x, lane = tid & 63, wid = tid >> 6;
    const int wm = wid / WCOLS, wn = wid % WCOLS;
    const int row0 = blockIdx.x * BM;
    if (MODE == 0) {
        for (int i = tid; i < 2 * BN; i += 512) (&sstat[0][0])[i] = 0.f;
    }
    f32x4 acc[M_REP][N_REP] = {};
    for (int side = 0; side < SIDES; ++side) {
        const ushort_t* A = side ? A2 : A1;
        const ushort_t* B = side ? B2 : B1;
        for (int kt = 0; kt < KP; kt += BK) {
            __syncthreads();  // protect LDS from prior iteration's readers
#pragma unroll
            for (int i = tid; i < BM * BK / 8; i += 512) {
                int r = i >> 3, c = i & 7;
                int gr = row0 + r;
                if (gr >= M) gr = M - 1;
                gload_lds16(A + (size_t)gr * KP + kt + c * 8, Alds + i * 8);
            }
#pragma unroll
            for (int i = tid; i < BN * BK / 8; i += 512) {
                int r = i >> 3, c = i & 7;
                gload_lds16(B + (size_t)r * KP + kt + c * 8, Blds + i * 8);
            }
            __syncthreads();
            bf16x8 a[2][M_REP], b[2][N_REP];
#pragma unroll
            for (int kk = 0; kk < 2; ++kk) {
#pragma unroll
                for (int m = 0; m < M_REP; ++m)
                    a[kk][m] = *(const bf16x8*)&Alds[(wm * WM + m * 16 + (lane & 15)) * BK + kk * 32 + (lane >> 4) * 8];
#pragma unroll
                for (int n = 0; n < N_REP; ++n)
                    b[kk][n] = *(const bf16x8*)&Blds[(wn * WN + n * 16 + (lane & 15)) * BK + kk * 32 + (lane >> 4) * 8];
            }
#pragma unroll
            for (int kk = 0; kk < 2; ++kk)
#pragma unroll
                for (int m = 0; m < M_REP; ++m)
#pragma unroll
                    for (int n = 0; n < N_REP; ++n)
                        acc[m][n] = __builtin_amdgcn_mfma_f32_16x16x32_bf16(a[kk][m], b[kk][n], acc[m][n], 0, 0, 0);
        }
    }
#pragma unroll
    for (int n = 0; n < N_REP; ++n) {
        int lcol = wn * WN + n * 16 + (lane & 15);
        float s = 0.f, q = 0.f;
#pragma unroll
        for (int m = 0; m < M_REP; ++m) {
#pragma unroll
            for (int r = 0; r < 4; ++r) {
                int row = row0 + wm * WM + m * 16 + (lane >> 4) * 4 + r;
                float v = acc[m][n][r];
                if (row < M) {
                    if (MODE == 0) {
                        out_bf[(size_t)row * 256 + lcol] = f2bf(v);
                        s += v;
                        q += v * v;
                    } else {
                        if (lcol < 64) {
                            out_bf[(size_t)row * 64 + lcol] = f2bf(v);
                        } else {
                            int c = lcol - 64;
                            float bv = (c < 47) ? bias[c] : 0.f;
                            out_f[(size_t)row * 64 + c] = v + bv;
                        }
                    }
                }
            }
        }
        if (MODE == 0) {
            s += __shfl_xor(s, 16); s += __shfl_xor(s, 32);
            q += __shfl_xor(q, 16); q += __shfl_xor(q, 32);
            if (lane < 16) {
                atomicAdd(&sstat[0][lcol], s);
                atomicAdd(&sstat[1][lcol], q);
            }
        }
    }
    if (MODE == 0) {
        __syncthreads();
        for (int i = tid; i < BN; i += 512) {
            atomicAdd(&stats[i], sstat[0][i]);
            atomicAdd(&stats[256 + i], sstat[1][i]);
        }
    }
}

// ---------- BN apply + ReLU, bf16 in / bf16 out, 16B vectorized ----------
__global__ void k_bnrelu(const ushort_t* __restrict__ h, const float* __restrict__ stats,
                         const float* __restrict__ g, const float* __restrict__ be,
                         int M, ushort_t* __restrict__ out) {
    int t = threadIdx.x;
    int cg = (t & 31) * 8;  // 8 cols per thread, 32 threads per row
    float invM = 1.f / (float)M;
    float sc[8], sh[8];
#pragma unroll
    for (int u = 0; u < 8; ++u) {
        int c = cg + u;
        float mean = stats[c] * invM;
        float var = stats[256 + c] * invM - mean * mean;
        float s = g[c] * rsqrtf(var + 1e-5f);
        sc[u] = s;
        sh[u] = be[c] - mean * s;
    }
    for (int r = blockIdx.x * 8 + (t >> 5); r < M; r += gridDim.x * 8) {
        uint4 d = *(const uint4*)(h + (size_t)r * 256 + cg);
        uint32 dd[4] = {d.x, d.y, d.z, d.w};
        uint32 w[4];
#pragma unroll
        for (int p = 0; p < 4; ++p) {
            float lo = bf2f((ushort_t)(dd[p] & 0xffff)) * sc[2 * p] + sh[2 * p];
            float hi = bf2f((ushort_t)(dd[p] >> 16)) * sc[2 * p + 1] + sh[2 * p + 1];
            w[p] = (uint32)f2bf(fmaxf(lo, 0.f)) | ((uint32)f2bf(fmaxf(hi, 0.f)) << 16);
        }
        uint4 o = {w[0], w[1], w[2], w[3]};
        *(uint4*)(out + (size_t)r * 256 + cg) = o;
    }
}

// ---------- layer 2: aggregate 64-dim transformed feats + log_softmax ----------
// Row = 128 B = 8 lanes x 16 B -> 8 edges/gather; 2 gathers in flight (int2 idx).
__global__ void k_agg_lsm(const ushort_t* __restrict__ t2, const float* __restrict__ r2,
                          const int* __restrict__ poffs, const int* __restrict__ deg,
                          const int* __restrict__ csr2, int N, float* __restrict__ out) {
    int wid = (blockIdx.x * blockDim.x + threadIdx.x) >> 6;
    int lane = threadIdx.x & 63;
    if (wid >= N) return;
    const int seg = lane & 7, sub = lane >> 3;
    int off = poffs[wid], cnt = deg[wid];
    int pcnt = (cnt + 15) & ~15;
    f32x2 acc[4] = {};
    const ushort_t* tp = t2 + seg * 8;
    int2 idx = *(const int2*)(csr2 + off + sub * 2);
    for (int b = 0; b < pcnt; b += 16) {
        uint4 d0 = *(const uint4*)(tp + (size_t)idx.x * 64);
        uint4 d1 = *(const uint4*)(tp + (size_t)idx.y * 64);
        int2 idxn = *(const int2*)(csr2 + off + b + 16 + sub * 2);
        uint32 dd[8] = {d0.x, d0.y, d0.z, d0.w, d1.x, d1.y, d1.z, d1.w};
#pragma unroll
        for (int q = 0; q < 8; ++q) {
            f32x2 tv;
            tv.x = asf(dd[q] << 16);
            tv.y = asf(dd[q] & 0xffff0000u);
            acc[q & 3] += tv;
        }
        idx = idxn;
    }
    float a[8] = {acc[0].x, acc[0].y, acc[1].x, acc[1].y,
                  acc[2].x, acc[2].y, acc[3].x, acc[3].y};
#pragma unroll
    for (int o = 8; o < 64; o <<= 1) {
#pragma unroll
        for (int k = 0; k < 8; ++k) a[k] += __shfl_xor(a[k], o);
    }
    if (sub == 0) {  // lanes 0..7 hold the full 64-dim row, 8 dims each
        float inv = 1.f / fmaxf((float)cnt, 1.f);
        float v[8];
#pragma unroll
        for (int k = 0; k < 8; ++k) {
            int c = seg * 8 + k;
            v[k] = a[k] * inv + r2[(size_t)wid * 64 + c];
            if (c >= 47) v[k] = -1e30f;
        }
        float m = v[0];
#pragma unroll
        for (int k = 1; k < 8; ++k) m = fmaxf(m, v[k]);
#pragma unroll
        for (int o = 1; o < 8; o <<= 1) m = fmaxf(m, __shfl_xor(m, o));
        float s = 0.f;
#pragma unroll
        for (int k = 0; k < 8; ++k) s += expf(v[k] - m);
#pragma unroll
        for (int o = 1; o < 8; o <<= 1) s += __shfl_xor(s, o);
        float lse = m + logf(s);
#pragma unroll
        for (int k = 0; k < 8; ++k) {
            int c = seg * 8 + k;
            if (c < 47) out[(size_t)wid * 47 + c] = v[k] - lse;
        }
    }
}

extern "C" void kernel_launch(void* const* d_in, const int* in_sizes, int n_in,
                              void* d_out, int out_size, void* d_ws, size_t ws_size,
                              hipStream_t stream) {
    const float* x   = (const float*)d_in[0];
    const int*   ei  = (const int*)d_in[1];
    const float* wl0 = (const float*)d_in[2];
    const float* wr0 = (const float*)d_in[3];
    const float* g0  = (const float*)d_in[5];
    const float* be0 = (const float*)d_in[6];
    const float* wl1 = (const float*)d_in[7];
    const float* wr1 = (const float*)d_in[8];
    const float* g1  = (const float*)d_in[10];
    const float* be1 = (const float*)d_in[11];
    const float* wl2 = (const float*)d_in[12];
    const float* wr2 = (const float*)d_in[13];
    const float* b2  = (const float*)d_in[14];
    float* out = (float*)d_out;

    const int N = in_sizes[0] / 100;
    const int E = in_sizes[1] / 2;
    const int* src = ei;
    const int* dst = ei + E;

    // workspace carve (256B aligned)
    char* p = (char*)d_ws;
    auto alloc = [&](size_t bytes) -> char* {
        char* r = p;
        p += (bytes + 255) & ~(size_t)255;
        return r;
    };
    const int NBLK = 128;
    const int nbins = (N + 1023) >> 10;           // 98 for N=100000
    const int scanN = nbins * NBLK;
    const size_t csr2N = (size_t)E + (size_t)nbins * 15376 + 64;
    ushort_t* xb   = (ushort_t*)alloc(((size_t)N + 1) * 128 * 2);   // +1 zero row
    ushort_t* hbuf = (ushort_t*)alloc(((size_t)N + 1) * 256 * 2);   // +1 zero row
    ushort_t* meanB = (ushort_t*)alloc(((size_t)N + 1) * 256 * 2);
    ushort_t* hpre = (ushort_t*)alloc((size_t)N * 256 * 2);
    int* deg   = (int*)alloc((size_t)N * 4);
    int* poffs = (int*)alloc((size_t)N * 4);
    int* csr2  = (int*)alloc(csr2N * 4);
    int* ebin  = (int*)alloc((size_t)E * 4);
    int* binCnt = (int*)alloc((size_t)scanN * 4);
    int* binOff = (int*)alloc((size_t)scanN * 4);
    int* bsum = (int*)alloc(1024 * 4);
    float* stats0 = (float*)alloc(512 * 4);
    float* stats1 = (float*)alloc(512 * 4);
    ushort_t* wlt0 = (ushort_t*)alloc(256 * 128 * 2);
    ushort_t* wrt0 = (ushort_t*)alloc(256 * 128 * 2);
    ushort_t* wlt1 = (ushort_t*)alloc(256 * 256 * 2);
    ushort_t* wrt1 = (ushort_t*)alloc(256 * 256 * 2);
    ushort_t* wcat2 = (ushort_t*)alloc(128 * 256 * 2);
    if ((size_t)(p - (char*)d_ws) > ws_size) return;  // insufficient scratch

    // layer-2 buffers alias meanB (dead after layer-1 GEMM); t2 has N+1 rows
    ushort_t* t2 = meanB;                                   // [N+1][64] bf16
    float*    r2 = (float*)(meanB + ((size_t)N + 1) * 64);  // [N][64] f32

    // zero rows / stats up front
    hipMemsetAsync(stats0, 0, 512 * 4, stream);
    hipMemsetAsync(stats1, 0, 512 * 4, stream);
    hipMemsetAsync(xb + (size_t)N * 128, 0, 128 * 2, stream);
    hipMemsetAsync(hbuf + (size_t)N * 256, 0, 256 * 2, stream);

    k_cast_x<<<2048, 256, 0, stream>>>(x, xb, N);
    k_cast_wall<<<896, 256, 0, stream>>>(wl0, wr0, wl1, wr1, wl2, wr2,
                                         wlt0, wrt0, wlt1, wrt1, wcat2);

    // ---- CSR build (binned counting sort, padded) ----
    const int CH = (E + NBLK - 1) / NBLK;
    k_bincount<<<NBLK, 256, 0, stream>>>(dst, E, CH, nbins, NBLK, binCnt);
    int NB2 = (scanN + 1023) / 1024;
    k_blocksum<<<NB2, 1024, 0, stream>>>(binCnt, scanN, bsum);
    k_scanb<<<1, 64, 0, stream>>>(bsum, NB2);
    k_exscan<<<NB2, 1024, 0, stream>>>(binCnt, bsum, scanN, binOff);
    k_binscatter<<<NBLK, 256, 0, stream>>>(src, dst, E, CH, nbins, NBLK, binOff, ebin);
    k_bincsr<<<nbins, 1024, 0, stream>>>(ebin, binOff, E, N, nbins, NBLK, poffs, deg, csr2);

    int aggBlocks = (N + 3) / 4;      // 4 waves (nodes) per 256-thread block
    int gemmM = (N + 127) / 128;

    // ---- layer 0 ----
    k_agg<128><<<aggBlocks, 256, 0, stream>>>(xb, poffs, deg, csr2, N, meanB);
    k_gemm<256, 2, 4, 0><<<gemmM, 512, 0, stream>>>(
        meanB, wlt0, xb, wrt0, 128, nullptr, hpre, nullptr, stats0, N);
    k_bnrelu<<<2048, 256, 0, stream>>>(hpre, stats0, g0, be0, N, hbuf);

    // ---- layer 1 ----
    k_agg<256><<<aggBlocks, 256, 0, stream>>>(hbuf, poffs, deg, csr2, N, meanB);
    k_gemm<256, 2, 4, 0><<<gemmM, 512, 0, stream>>>(
        meanB, wlt1, hbuf, wrt1, 256, nullptr, hpre, nullptr, stats1, N);
    k_bnrelu<<<2048, 256, 0, stream>>>(hpre, stats1, g1, be1, N, hbuf);

    // ---- layer 2 (transform-first: mean(h)@wl2 == mean(h@wl2)) ----
    hipMemsetAsync(t2 + (size_t)N * 64, 0, 64 * 2, stream);  // zero row for padding
    k_gemm<128, 2, 4, 1><<<gemmM, 512, 0, stream>>>(
        hbuf, wcat2, nullptr, nullptr, 256, b2, t2, r2, nullptr, N);
    k_agg_lsm<<<(N + 3) / 4, 256, 0, stream>>>(t2, r2, poffs, deg, csr2, N, out);
}

// Round 9
// 534.546 us; speedup vs baseline: 1.0517x; 1.0517x over previous
//
#include <hip/hip_runtime.h>
#include <hip/hip_bf16.h>
#include <math.h>

#define DEVFN __device__ __forceinline__

typedef unsigned int uint32;
typedef unsigned short ushort_t;

using bf16x8 = __attribute__((ext_vector_type(8))) short;
using f32x4  = __attribute__((ext_vector_type(4))) float;
using f32x2  = __attribute__((ext_vector_type(2))) float;

DEVFN float bf2f(ushort_t u) {
    union { uint32 i; float f; } v; v.i = ((uint32)u) << 16; return v.f;
}
DEVFN float asf(uint32 u) {
    union { uint32 i; float f; } v; v.i = u; return v.f;
}
DEVFN ushort_t f2bf(float f) {
    union { float f; uint32 i; } v; v.f = f;
    uint32 u = v.i;
    uint32 r = (u + 0x7FFFu + ((u >> 16) & 1u)) >> 16;
    return (ushort_t)r;
}

DEVFN void gload_lds16(const void* g, void* l) {
    __builtin_amdgcn_global_load_lds(
        (const __attribute__((address_space(1))) void*)g,
        (__attribute__((address_space(3))) void*)l, 16, 0, 0);
}

// ---------- zero scratch (replaces 4 memsets) ----------
__global__ void k_zero(float* __restrict__ stats0, float* __restrict__ stats1,
                       ushort_t* __restrict__ xrow, ushort_t* __restrict__ hrow) {
    int t = threadIdx.x;
    if (t < 512) { stats0[t] = 0.f; stats1[t] = 0.f; }
    if (t < 128) xrow[t] = 0;
    if (t < 256) hrow[t] = 0;
}

// ---------- casts ----------
__global__ void k_cast_x(const float* __restrict__ x, ushort_t* __restrict__ xb, int N) {
    int total = N * 128;
    for (int i = blockIdx.x * blockDim.x + threadIdx.x; i < total; i += gridDim.x * blockDim.x) {
        int col = i & 127, row = i >> 7;
        float v = (col < 100) ? x[row * 100 + col] : 0.f;
        xb[i] = f2bf(v);
    }
}

DEVFN void cast_one(const float* __restrict__ w, ushort_t* __restrict__ wt,
                    int j, int K, int Nout, int Kp) {
    int k = j % Kp, n = j / Kp;
    float v = (k < K && n < Nout) ? w[k * Nout + n] : 0.f;
    wt[j] = f2bf(v);
}

// all 6 weight transposes in one kernel (fixed sizes)
__global__ void k_cast_wall(const float* __restrict__ wl0, const float* __restrict__ wr0,
                            const float* __restrict__ wl1, const float* __restrict__ wr1,
                            const float* __restrict__ wl2, const float* __restrict__ wr2,
                            ushort_t* __restrict__ wlt0, ushort_t* __restrict__ wrt0,
                            ushort_t* __restrict__ wlt1, ushort_t* __restrict__ wrt1,
                            ushort_t* __restrict__ wcat2) {
    const int total = 229376;
    for (int i = blockIdx.x * blockDim.x + threadIdx.x; i < total; i += gridDim.x * blockDim.x) {
        int j = i;
        if (j < 32768)        cast_one(wl0, wlt0, j, 100, 256, 128);
        else if (j < 65536)   cast_one(wr0, wrt0, j - 32768, 100, 256, 128);
        else if (j < 131072)  cast_one(wl1, wlt1, j - 65536, 256, 256, 256);
        else if (j < 196608)  cast_one(wr1, wrt1, j - 131072, 256, 256, 256);
        else if (j < 212992)  cast_one(wl2, wcat2, j - 196608, 256, 47, 256);
        else                  cast_one(wr2, wcat2 + 16384, j - 212992, 256, 47, 256);
    }
}

// ---------- CSR build: binned counting sort by dst>>10, PADDED to 16 ----------
__global__ void k_bincount(const int* __restrict__ dst, int E, int CH, int nbins, int nblk,
                           int* __restrict__ binCnt) {
    __shared__ int scnt[128];
    int blk = blockIdx.x, tid = threadIdx.x;
    for (int b = tid; b < 128; b += 256) scnt[b] = 0;
    __syncthreads();
    int e0 = blk * CH, e1 = min(E, e0 + CH);
    for (int i = e0 + tid; i < e1; i += 256)
        atomicAdd(&scnt[dst[i] >> 10], 1);
    __syncthreads();
    for (int b = tid; b < nbins; b += 256) binCnt[b * nblk + blk] = scnt[b];
}

// single-block exclusive scan over n <= 16384 entries (PER=16 per thread)
__global__ void k_scan_all(const int* __restrict__ v, int n, int* __restrict__ outOff) {
    __shared__ int s[1024];
    int t = threadIdx.x;
    int b0 = t * 16;
    int loc[16];
    int sum = 0;
#pragma unroll
    for (int k = 0; k < 16; ++k) {
        int x = (b0 + k < n) ? v[b0 + k] : 0;
        loc[k] = x;
        sum += x;
    }
    s[t] = sum;
    __syncthreads();
    for (int o = 1; o < 1024; o <<= 1) {
        int add = (t >= o) ? s[t - o] : 0;
        __syncthreads();
        s[t] += add;
        __syncthreads();
    }
    int run = s[t] - sum;   // exclusive prefix of this thread's chunk
#pragma unroll
    for (int k = 0; k < 16; ++k) {
        if (b0 + k < n) outOff[b0 + k] = run;
        run += loc[k];
    }
}

__global__ void k_binscatter(const int* __restrict__ src, const int* __restrict__ dst,
                             int E, int CH, int nbins, int nblk,
                             const int* __restrict__ binOff, int* __restrict__ ebin) {
    __shared__ int scur[128];
    int blk = blockIdx.x, tid = threadIdx.x;
    for (int b = tid; b < nbins; b += 256) scur[b] = binOff[b * nblk + blk];
    __syncthreads();
    int e0 = blk * CH, e1 = min(E, e0 + CH);
    for (int i = e0 + tid; i < e1; i += 256) {
        int d = dst[i];
        int b = d >> 10;
        int pos = atomicAdd(&scur[b], 1);
        ebin[pos] = (src[i] << 10) | (d & 1023);
    }
}

// Per-bin CSR finalize with per-node padding to multiple of 16.
// Pad entries point to node N (a zeroed feature row). Per-bin padded base:
// pbase = align16(binStart) + bin*15376 (>= sum of previous bins' padded sizes).
__global__ void k_bincsr(const int* __restrict__ ebin, const int* __restrict__ binOff,
                         int E, int N, int nbins, int nblk,
                         int* __restrict__ poffs, int* __restrict__ deg, int* __restrict__ csr2) {
    __shared__ int sdeg[1024];
    __shared__ int scur[1024];
    int bin = blockIdx.x, t = threadIdx.x;
    int binStart = binOff[bin * nblk];
    int binEnd = (bin + 1 < nbins) ? binOff[(bin + 1) * nblk] : E;
    int pbase = ((binStart + 15) & ~15) + bin * 15376;
    sdeg[t] = 0;
    __syncthreads();
    for (int i = binStart + t; i < binEnd; i += 1024)
        atomicAdd(&sdeg[ebin[i] & 1023], 1);
    __syncthreads();
    int v = sdeg[t];
    int pv = (v + 15) & ~15;
    sdeg[t] = pv;
    __syncthreads();
    for (int o = 1; o < 1024; o <<= 1) {
        int add = (t >= o) ? sdeg[t - o] : 0;
        __syncthreads();
        sdeg[t] += add;
        __syncthreads();
    }
    int pex = sdeg[t] - pv;
    int node = bin * 1024 + t;
    if (node < N) { poffs[node] = pbase + pex; deg[node] = v; }
    scur[t] = pex;
    __syncthreads();
    for (int i = binStart + t; i < binEnd; i += 1024) {
        int e = ebin[i];
        int slot = atomicAdd(&scur[e & 1023], 1);
        csr2[pbase + slot] = e >> 10;
    }
    for (int j = v; j < pv; ++j) csr2[pbase + pex + j] = N;  // padding -> zero row
}

// ---------- aggregation: wave per node, padded edge lists, no masks ----------
template <int D>
__global__ __launch_bounds__(256) void k_agg(
    const ushort_t* __restrict__ h, const int* __restrict__ poffs,
    const int* __restrict__ deg, const int* __restrict__ csr2,
    int N, ushort_t* __restrict__ mean) {
    constexpr int LPR = D / 8;        // lanes per row
    constexpr int EPG = 64 / LPR;     // edges per gather
    constexpr int STEP = 4 * EPG;     // edges per iteration
    int wid = (blockIdx.x * blockDim.x + threadIdx.x) >> 6;
    int lane = threadIdx.x & 63;
    if (wid >= N) return;
    const int seg = lane % LPR, sub = lane / LPR;
    int off = poffs[wid], cnt = deg[wid];
    int pcnt = (cnt + 15) & ~15;
    f32x2 acc[4] = {};
    const ushort_t* hp = h + seg * 8;
    int4 idx = *(const int4*)(csr2 + off + sub * 4);
    for (int b = 0; b < pcnt; b += STEP) {
        uint4 d0 = *(const uint4*)(hp + (size_t)idx.x * D);
        uint4 d1 = *(const uint4*)(hp + (size_t)idx.y * D);
        uint4 d2 = *(const uint4*)(hp + (size_t)idx.z * D);
        uint4 d3 = *(const uint4*)(hp + (size_t)idx.w * D);
        int4 idxn = *(const int4*)(csr2 + off + b + STEP + sub * 4);
        uint32 dd[16] = {d0.x, d0.y, d0.z, d0.w, d1.x, d1.y, d1.z, d1.w,
                         d2.x, d2.y, d2.z, d2.w, d3.x, d3.y, d3.z, d3.w};
#pragma unroll
        for (int q = 0; q < 16; ++q) {
            f32x2 tv;
            tv.x = asf(dd[q] << 16);
            tv.y = asf(dd[q] & 0xffff0000u);
            acc[q & 3] += tv;
        }
        idx = idxn;
    }
    float a[8] = {acc[0].x, acc[0].y, acc[1].x, acc[1].y,
                  acc[2].x, acc[2].y, acc[3].x, acc[3].y};
#pragma unroll
    for (int o = LPR; o < 64; o <<= 1) {
#pragma unroll
        for (int k = 0; k < 8; ++k) a[k] += __shfl_xor(a[k], o);
    }
    if (sub == 0) {
        float inv = 1.f / fmaxf((float)cnt, 1.f);
        uint4 o4;
        o4.x = (uint32)f2bf(a[0] * inv) | ((uint32)f2bf(a[1] * inv) << 16);
        o4.y = (uint32)f2bf(a[2] * inv) | ((uint32)f2bf(a[3] * inv) << 16);
        o4.z = (uint32)f2bf(a[4] * inv) | ((uint32)f2bf(a[5] * inv) << 16);
        o4.w = (uint32)f2bf(a[6] * inv) | ((uint32)f2bf(a[7] * inv) << 16);
        *(uint4*)(mean + (size_t)wid * D + seg * 8) = o4;
    }
}

// ---------- B-stationary register GEMM ----------
// B panel (<=256 KB) lives in VGPRs: wave wv owns cols [wv*16*N_REP, +16*N_REP).
// A streamed: full-K rows staged to LDS (double-buffered), ONE barrier per tile.
// MODE 0: out = A1@B1^T + A2@B2^T, bf16 [M][256], BN stats in regs -> 2 atomics/lane.
// MODE 1: out = A1@B1^T; cols 0..63 -> bf16 t2 [M][64], 64..127 -> f32 r2 (+bias).
template <int KP, int MODE>
__global__ __launch_bounds__(512) void k_gemm2(
    const ushort_t* __restrict__ A1, const ushort_t* __restrict__ B1,
    const ushort_t* __restrict__ A2, const ushort_t* __restrict__ B2,
    const float* __restrict__ bias,
    ushort_t* __restrict__ out_bf, float* __restrict__ out_f,
    float* __restrict__ stats, int M, int nTiles) {
    constexpr int SIDES = (MODE == 0) ? 2 : 1;
    constexpr int N_REP = (MODE == 0) ? 2 : 1;
    constexpr int KCH = KP / 32;                       // MFMA k-chunks
    constexpr int JW = KP / 8;                         // 16B units per row
    constexpr int TILE = (MODE == 0 && KP == 256) ? 32 : 64;
    constexpr int M_REP = TILE / 16;
    constexpr int SLOTS = SIDES * TILE * JW;           // 16B slots per buffer
    __shared__ ushort_t Alds[2][SLOTS * 8];            // 2 x 32KB
    const int tid = threadIdx.x, lane = tid & 63, wv = tid >> 6;
    const int colBase = wv * (16 * N_REP) + (lane & 15);

    // B panel -> registers (L2-hot after first blocks)
    bf16x8 b[SIDES][KCH][N_REP];
#pragma unroll
    for (int s = 0; s < SIDES; ++s) {
        const ushort_t* B = s ? B2 : B1;
#pragma unroll
        for (int n = 0; n < N_REP; ++n)
#pragma unroll
            for (int c = 0; c < KCH; ++c)
                b[s][c][n] = *(const bf16x8*)&B[(size_t)(colBase + n * 16) * KP + c * 32 + (lane >> 4) * 8];
    }
    float bval = 0.f;
    if (MODE == 1) {
        int c2 = colBase - 64;
        bval = (c2 >= 0 && c2 < 47) ? bias[c2] : 0.f;
    }
    float ssum[N_REP] = {}, ssq[N_REP] = {};

    auto STAGE = [&](int t, int buf) {
        int r0 = t * TILE;
#pragma unroll
        for (int i = tid; i < SLOTS; i += 512) {
            int side = i / (TILE * JW);
            int rem = i - side * (TILE * JW);
            int r = rem / JW, j = rem - r * JW;
            int gr = min(r0 + r, M - 1);
            const ushort_t* Asrc = side ? A2 : A1;
            gload_lds16(Asrc + (size_t)gr * KP + j * 8, &Alds[buf][(size_t)i * 8]);
        }
    };

    int t0 = blockIdx.x;
    if (t0 < nTiles) STAGE(t0, 0);
    int buf = 0;
    for (int t = t0; t < nTiles; t += gridDim.x) {
        __syncthreads();                       // stage(buf) landed; prior reads done
        int tn = t + gridDim.x;
        if (tn < nTiles) STAGE(tn, buf ^ 1);   // async, hides under MFMA below
        f32x4 acc[M_REP][N_REP] = {};
#pragma unroll
        for (int s = 0; s < SIDES; ++s) {
            const ushort_t* base = &Alds[buf][s * TILE * JW * 8];
#pragma unroll
            for (int m = 0; m < M_REP; ++m) {
                bf16x8 a8[KCH];
#pragma unroll
                for (int c = 0; c < KCH; ++c)
                    a8[c] = *(const bf16x8*)&base[(m * 16 + (lane & 15)) * KP + c * 32 + (lane >> 4) * 8];
#pragma unroll
                for (int c = 0; c < KCH; ++c)
#pragma unroll
                    for (int n = 0; n < N_REP; ++n)
                        acc[m][n] = __builtin_amdgcn_mfma_f32_16x16x32_bf16(a8[c], b[s][c][n], acc[m][n], 0, 0, 0);
            }
        }
        int r0 = t * TILE;
#pragma unroll
        for (int n = 0; n < N_REP; ++n) {
            int col = colBase + n * 16;
#pragma unroll
            for (int m = 0; m < M_REP; ++m) {
#pragma unroll
                for (int r = 0; r < 4; ++r) {
                    int row = r0 + m * 16 + (lane >> 4) * 4 + r;
                    float v = acc[m][n][r];
                    if (row < M) {
                        if (MODE == 0) {
                            out_bf[(size_t)row * 256 + col] = f2bf(v);
                            ssum[n] += v;
                            ssq[n] += v * v;
                        } else {
                            if (col < 64) out_bf[(size_t)row * 64 + col] = f2bf(v);
                            else out_f[(size_t)row * 64 + (col - 64)] = v + bval;
                        }
                    }
                }
            }
        }
        buf ^= 1;
    }
    if (MODE == 0) {
#pragma unroll
        for (int n = 0; n < N_REP; ++n) {
            float s = ssum[n], q = ssq[n];
            s += __shfl_xor(s, 16); s += __shfl_xor(s, 32);
            q += __shfl_xor(q, 16); q += __shfl_xor(q, 32);
            if (lane < 16) {
                atomicAdd(&stats[colBase + n * 16], s);
                atomicAdd(&stats[256 + colBase + n * 16], q);
            }
        }
    }
}

// ---------- BN apply + ReLU, bf16 in / bf16 out, 16B vectorized ----------
__global__ void k_bnrelu(const ushort_t* __restrict__ h, const float* __restrict__ stats,
                         const float* __restrict__ g, const float* __restrict__ be,
                         int M, ushort_t* __restrict__ out) {
    int t = threadIdx.x;
    int cg = (t & 31) * 8;  // 8 cols per thread, 32 threads per row
    float invM = 1.f / (float)M;
    float sc[8], sh[8];
#pragma unroll
    for (int u = 0; u < 8; ++u) {
        int c = cg + u;
        float mean = stats[c] * invM;
        float var = stats[256 + c] * invM - mean * mean;
        float s = g[c] * rsqrtf(var + 1e-5f);
        sc[u] = s;
        sh[u] = be[c] - mean * s;
    }
    for (int r = blockIdx.x * 8 + (t >> 5); r < M; r += gridDim.x * 8) {
        uint4 d = *(const uint4*)(h + (size_t)r * 256 + cg);
        uint32 dd[4] = {d.x, d.y, d.z, d.w};
        uint32 w[4];
#pragma unroll
        for (int p = 0; p < 4; ++p) {
            float lo = bf2f((ushort_t)(dd[p] & 0xffff)) * sc[2 * p] + sh[2 * p];
            float hi = bf2f((ushort_t)(dd[p] >> 16)) * sc[2 * p + 1] + sh[2 * p + 1];
            w[p] = (uint32)f2bf(fmaxf(lo, 0.f)) | ((uint32)f2bf(fmaxf(hi, 0.f)) << 16);
        }
        uint4 o = {w[0], w[1], w[2], w[3]};
        *(uint4*)(out + (size_t)r * 256 + cg) = o;
    }
}

// ---------- layer 2: aggregate 64-dim transformed feats + log_softmax ----------
__global__ void k_agg_lsm(const ushort_t* __restrict__ t2, const float* __restrict__ r2,
                          const int* __restrict__ poffs, const int* __restrict__ deg,
                          const int* __restrict__ csr2, int N, float* __restrict__ out) {
    int wid = (blockIdx.x * blockDim.x + threadIdx.x) >> 6;
    int lane = threadIdx.x & 63;
    if (wid >= N) return;
    const int seg = lane & 7, sub = lane >> 3;
    int off = poffs[wid], cnt = deg[wid];
    int pcnt = (cnt + 15) & ~15;
    f32x2 acc[4] = {};
    const ushort_t* tp = t2 + seg * 8;
    int2 idx = *(const int2*)(csr2 + off + sub * 2);
    for (int b = 0; b < pcnt; b += 16) {
        uint4 d0 = *(const uint4*)(tp + (size_t)idx.x * 64);
        uint4 d1 = *(const uint4*)(tp + (size_t)idx.y * 64);
        int2 idxn = *(const int2*)(csr2 + off + b + 16 + sub * 2);
        uint32 dd[8] = {d0.x, d0.y, d0.z, d0.w, d1.x, d1.y, d1.z, d1.w};
#pragma unroll
        for (int q = 0; q < 8; ++q) {
            f32x2 tv;
            tv.x = asf(dd[q] << 16);
            tv.y = asf(dd[q] & 0xffff0000u);
            acc[q & 3] += tv;
        }
        idx = idxn;
    }
    float a[8] = {acc[0].x, acc[0].y, acc[1].x, acc[1].y,
                  acc[2].x, acc[2].y, acc[3].x, acc[3].y};
#pragma unroll
    for (int o = 8; o < 64; o <<= 1) {
#pragma unroll
        for (int k = 0; k < 8; ++k) a[k] += __shfl_xor(a[k], o);
    }
    if (sub == 0) {  // lanes 0..7 hold the full 64-dim row, 8 dims each
        float inv = 1.f / fmaxf((float)cnt, 1.f);
        float v[8];
#pragma unroll
        for (int k = 0; k < 8; ++k) {
            int c = seg * 8 + k;
            v[k] = a[k] * inv + r2[(size_t)wid * 64 + c];
            if (c >= 47) v[k] = -1e30f;
        }
        float m = v[0];
#pragma unroll
        for (int k = 1; k < 8; ++k) m = fmaxf(m, v[k]);
#pragma unroll
        for (int o = 1; o < 8; o <<= 1) m = fmaxf(m, __shfl_xor(m, o));
        float s = 0.f;
#pragma unroll
        for (int k = 0; k < 8; ++k) s += expf(v[k] - m);
#pragma unroll
        for (int o = 1; o < 8; o <<= 1) s += __shfl_xor(s, o);
        float lse = m + logf(s);
#pragma unroll
        for (int k = 0; k < 8; ++k) {
            int c = seg * 8 + k;
            if (c < 47) out[(size_t)wid * 47 + c] = v[k] - lse;
        }
    }
}

extern "C" void kernel_launch(void* const* d_in, const int* in_sizes, int n_in,
                              void* d_out, int out_size, void* d_ws, size_t ws_size,
                              hipStream_t stream) {
    const float* x   = (const float*)d_in[0];
    const int*   ei  = (const int*)d_in[1];
    const float* wl0 = (const float*)d_in[2];
    const float* wr0 = (const float*)d_in[3];
    const float* g0  = (const float*)d_in[5];
    const float* be0 = (const float*)d_in[6];
    const float* wl1 = (const float*)d_in[7];
    const float* wr1 = (const float*)d_in[8];
    const float* g1  = (const float*)d_in[10];
    const float* be1 = (const float*)d_in[11];
    const float* wl2 = (const float*)d_in[12];
    const float* wr2 = (const float*)d_in[13];
    const float* b2  = (const float*)d_in[14];
    float* out = (float*)d_out;

    const int N = in_sizes[0] / 100;
    const int E = in_sizes[1] / 2;
    const int* src = ei;
    const int* dst = ei + E;

    // workspace carve (256B aligned)
    char* p = (char*)d_ws;
    auto alloc = [&](size_t bytes) -> char* {
        char* r = p;
        p += (bytes + 255) & ~(size_t)255;
        return r;
    };
    const int NBLK = 128;
    const int nbins = (N + 1023) >> 10;           // 98 for N=100000
    const int scanN = nbins * NBLK;
    const size_t csr2N = (size_t)E + (size_t)nbins * 15376 + 64;
    ushort_t* xb   = (ushort_t*)alloc(((size_t)N + 1) * 128 * 2);   // +1 zero row
    ushort_t* hbuf = (ushort_t*)alloc(((size_t)N + 1) * 256 * 2);   // +1 zero row
    ushort_t* meanB = (ushort_t*)alloc(((size_t)N + 1) * 256 * 2);
    ushort_t* hpre = (ushort_t*)alloc((size_t)N * 256 * 2);
    int* deg   = (int*)alloc((size_t)N * 4);
    int* poffs = (int*)alloc((size_t)N * 4);
    int* csr2  = (int*)alloc(csr2N * 4);
    int* ebin  = (int*)alloc((size_t)E * 4);
    int* binCnt = (int*)alloc((size_t)scanN * 4);
    int* binOff = (int*)alloc((size_t)scanN * 4);
    float* stats0 = (float*)alloc(512 * 4);
    float* stats1 = (float*)alloc(512 * 4);
    ushort_t* wlt0 = (ushort_t*)alloc(256 * 128 * 2);
    ushort_t* wrt0 = (ushort_t*)alloc(256 * 128 * 2);
    ushort_t* wlt1 = (ushort_t*)alloc(256 * 256 * 2);
    ushort_t* wrt1 = (ushort_t*)alloc(256 * 256 * 2);
    ushort_t* wcat2 = (ushort_t*)alloc(128 * 256 * 2);
    if ((size_t)(p - (char*)d_ws) > ws_size) return;  // insufficient scratch

    // layer-2 buffers alias meanB (dead after layer-1 GEMM); t2 has N+1 rows
    ushort_t* t2 = meanB;                                   // [N+1][64] bf16
    float*    r2 = (float*)(meanB + ((size_t)N + 1) * 64);  // [N][64] f32

    k_zero<<<1, 1024, 0, stream>>>(stats0, stats1, xb + (size_t)N * 128, hbuf + (size_t)N * 256);
    k_cast_x<<<2048, 256, 0, stream>>>(x, xb, N);
    k_cast_wall<<<896, 256, 0, stream>>>(wl0, wr0, wl1, wr1, wl2, wr2,
                                         wlt0, wrt0, wlt1, wrt1, wcat2);

    // ---- CSR build (binned counting sort, padded) ----
    const int CH = (E + NBLK - 1) / NBLK;
    k_bincount<<<NBLK, 256, 0, stream>>>(dst, E, CH, nbins, NBLK, binCnt);
    k_scan_all<<<1, 1024, 0, stream>>>(binCnt, scanN, binOff);
    k_binscatter<<<NBLK, 256, 0, stream>>>(src, dst, E, CH, nbins, NBLK, binOff, ebin);
    k_bincsr<<<nbins, 1024, 0, stream>>>(ebin, binOff, E, N, nbins, NBLK, poffs, deg, csr2);

    int aggBlocks = (N + 3) / 4;      // 4 waves (nodes) per 256-thread block
    int tiles64 = (N + 63) / 64;
    int tiles32 = (N + 31) / 32;

    // ---- layer 0 ----
    k_agg<128><<<aggBlocks, 256, 0, stream>>>(xb, poffs, deg, csr2, N, meanB);
    k_gemm2<128, 0><<<256, 512, 0, stream>>>(
        meanB, wlt0, xb, wrt0, nullptr, hpre, nullptr, stats0, N, tiles64);
    k_bnrelu<<<2048, 256, 0, stream>>>(hpre, stats0, g0, be0, N, hbuf);

    // ---- layer 1 ----
    k_agg<256><<<aggBlocks, 256, 0, stream>>>(hbuf, poffs, deg, csr2, N, meanB);
    k_gemm2<256, 0><<<256, 512, 0, stream>>>(
        meanB, wlt1, hbuf, wrt1, nullptr, hpre, nullptr, stats1, N, tiles32);
    k_bnrelu<<<2048, 256, 0, stream>>>(hpre, stats1, g1, be1, N, hbuf);

    // ---- layer 2 (transform-first: mean(h)@wl2 == mean(h@wl2)) ----
    hipMemsetAsync(t2 + (size_t)N * 64, 0, 64 * 2, stream);  // zero row for padding
    k_gemm2<256, 1><<<512, 512, 0, stream>>>(
        hbuf, wcat2, nullptr, nullptr, b2, t2, r2, nullptr, N, tiles64);
    k_agg_lsm<<<(N + 3) / 4, 256, 0, stream>>>(t2, r2, poffs, deg, csr2, N, out);
}

// Round 11
// 534.136 us; speedup vs baseline: 1.0525x; 1.0008x over previous
//
#include <hip/hip_runtime.h>
#include <hip/hip_bf16.h>
#include <math.h>

#define DEVFN __device__ __forceinline__

typedef unsigned int uint32;
typedef unsigned short ushort_t;

using bf16x8 = __attribute__((ext_vector_type(8))) short;
using f32x4  = __attribute__((ext_vector_type(4))) float;
using f32x2  = __attribute__((ext_vector_type(2))) float;

DEVFN float bf2f(ushort_t u) {
    union { uint32 i; float f; } v; v.i = ((uint32)u) << 16; return v.f;
}
DEVFN float asf(uint32 u) {
    union { uint32 i; float f; } v; v.i = u; return v.f;
}
DEVFN ushort_t f2bf(float f) {
    union { float f; uint32 i; } v; v.f = f;
    uint32 u = v.i;
    uint32 r = (u + 0x7FFFu + ((u >> 16) & 1u)) >> 16;
    return (ushort_t)r;
}

DEVFN void gload_lds16(const void* g, void* l) {
    __builtin_amdgcn_global_load_lds(
        (const __attribute__((address_space(1))) void*)g,
        (__attribute__((address_space(3))) void*)l, 16, 0, 0);
}

// ---------- cast x (+ block 0 zeroes stats & pad rows, stride loop: 256 thr) ----------
__global__ void k_cast_x(const float* __restrict__ x, ushort_t* __restrict__ xb, int N,
                         float* __restrict__ stats0, float* __restrict__ stats1,
                         ushort_t* __restrict__ xrow, ushort_t* __restrict__ hrow) {
    if (blockIdx.x == 0) {
        for (int t = threadIdx.x; t < 512; t += blockDim.x) {
            stats0[t] = 0.f;
            stats1[t] = 0.f;
        }
        for (int t = threadIdx.x; t < 128; t += blockDim.x) xrow[t] = 0;
        for (int t = threadIdx.x; t < 256; t += blockDim.x) hrow[t] = 0;
    }
    int total = N * 128;
    for (int i = blockIdx.x * blockDim.x + threadIdx.x; i < total; i += gridDim.x * blockDim.x) {
        int col = i & 127, row = i >> 7;
        float v = (col < 100) ? x[row * 100 + col] : 0.f;
        xb[i] = f2bf(v);
    }
}

DEVFN void cast_one(const float* __restrict__ w, ushort_t* __restrict__ wt,
                    int j, int K, int Nout, int Kp) {
    int k = j % Kp, n = j / Kp;
    float v = (k < K && n < Nout) ? w[k * Nout + n] : 0.f;
    wt[j] = f2bf(v);
}

// all 6 weight transposes in one kernel (fixed sizes)
__global__ void k_cast_wall(const float* __restrict__ wl0, const float* __restrict__ wr0,
                            const float* __restrict__ wl1, const float* __restrict__ wr1,
                            const float* __restrict__ wl2, const float* __restrict__ wr2,
                            ushort_t* __restrict__ wlt0, ushort_t* __restrict__ wrt0,
                            ushort_t* __restrict__ wlt1, ushort_t* __restrict__ wrt1,
                            ushort_t* __restrict__ wcat2) {
    const int total = 229376;
    for (int i = blockIdx.x * blockDim.x + threadIdx.x; i < total; i += gridDim.x * blockDim.x) {
        int j = i;
        if (j < 32768)        cast_one(wl0, wlt0, j, 100, 256, 128);
        else if (j < 65536)   cast_one(wr0, wrt0, j - 32768, 100, 256, 128);
        else if (j < 131072)  cast_one(wl1, wlt1, j - 65536, 256, 256, 256);
        else if (j < 196608)  cast_one(wr1, wrt1, j - 131072, 256, 256, 256);
        else if (j < 212992)  cast_one(wl2, wcat2, j - 196608, 256, 47, 256);
        else                  cast_one(wr2, wcat2 + 16384, j - 212992, 256, 47, 256);
    }
}

// ---------- CSR build: binned counting sort by dst>>10, PADDED to 16 ----------
__global__ void k_bincount(const int* __restrict__ dst, int E, int CH, int nbins, int nblk,
                           int* __restrict__ binCnt) {
    __shared__ int scnt[128];
    int blk = blockIdx.x, tid = threadIdx.x;
    for (int b = tid; b < 128; b += 256) scnt[b] = 0;
    __syncthreads();
    int e0 = blk * CH, e1 = min(E, e0 + CH);
    for (int i = e0 + tid; i < e1; i += 256)
        atomicAdd(&scnt[dst[i] >> 10], 1);
    __syncthreads();
    for (int b = tid; b < nbins; b += 256) binCnt[b * nblk + blk] = scnt[b];
}

// single-block exclusive scan over n <= 16384 entries (PER=16 per thread)
__global__ void k_scan_all(const int* __restrict__ v, int n, int* __restrict__ outOff) {
    __shared__ int s[1024];
    int t = threadIdx.x;
    int b0 = t * 16;
    int loc[16];
    int sum = 0;
#pragma unroll
    for (int k = 0; k < 16; ++k) {
        int x = (b0 + k < n) ? v[b0 + k] : 0;
        loc[k] = x;
        sum += x;
    }
    s[t] = sum;
    __syncthreads();
    for (int o = 1; o < 1024; o <<= 1) {
        int add = (t >= o) ? s[t - o] : 0;
        __syncthreads();
        s[t] += add;
        __syncthreads();
    }
    int run = s[t] - sum;   // exclusive prefix of this thread's chunk
#pragma unroll
    for (int k = 0; k < 16; ++k) {
        if (b0 + k < n) outOff[b0 + k] = run;
        run += loc[k];
    }
}

__global__ void k_binscatter(const int* __restrict__ src, const int* __restrict__ dst,
                             int E, int CH, int nbins, int nblk,
                             const int* __restrict__ binOff, int* __restrict__ ebin) {
    __shared__ int scur[128];
    int blk = blockIdx.x, tid = threadIdx.x;
    for (int b = tid; b < nbins; b += 256) scur[b] = binOff[b * nblk + blk];
    __syncthreads();
    int e0 = blk * CH, e1 = min(E, e0 + CH);
    for (int i = e0 + tid; i < e1; i += 256) {
        int d = dst[i];
        int b = d >> 10;
        int pos = atomicAdd(&scur[b], 1);
        ebin[pos] = (src[i] << 10) | (d & 1023);
    }
}

// Per-bin CSR finalize with per-node padding to multiple of 16.
// Pad entries point to node N (a zeroed feature row). Per-bin padded base:
// pbase = align16(binStart) + bin*15376 (>= sum of previous bins' padded sizes).
__global__ void k_bincsr(const int* __restrict__ ebin, const int* __restrict__ binOff,
                         int E, int N, int nbins, int nblk,
                         int* __restrict__ poffs, int* __restrict__ deg, int* __restrict__ csr2) {
    __shared__ int sdeg[1024];
    __shared__ int scur[1024];
    int bin = blockIdx.x, t = threadIdx.x;
    int binStart = binOff[bin * nblk];
    int binEnd = (bin + 1 < nbins) ? binOff[(bin + 1) * nblk] : E;
    int pbase = ((binStart + 15) & ~15) + bin * 15376;
    sdeg[t] = 0;
    __syncthreads();
    for (int i = binStart + t; i < binEnd; i += 1024)
        atomicAdd(&sdeg[ebin[i] & 1023], 1);
    __syncthreads();
    int v = sdeg[t];
    int pv = (v + 15) & ~15;
    sdeg[t] = pv;
    __syncthreads();
    for (int o = 1; o < 1024; o <<= 1) {
        int add = (t >= o) ? sdeg[t - o] : 0;
        __syncthreads();
        sdeg[t] += add;
        __syncthreads();
    }
    int pex = sdeg[t] - pv;
    int node = bin * 1024 + t;
    if (node < N) { poffs[node] = pbase + pex; deg[node] = v; }
    scur[t] = pex;
    __syncthreads();
    for (int i = binStart + t; i < binEnd; i += 1024) {
        int e = ebin[i];
        int slot = atomicAdd(&scur[e & 1023], 1);
        csr2[pbase + slot] = e >> 10;
    }
    for (int j = v; j < pv; ++j) csr2[pbase + pex + j] = N;  // padding -> zero row
}

// ---------- aggregation: wave per node, padded edge lists, no masks ----------
// BATCH uint4 gathers in flight; STEP = BATCH*EPG must equal the pad quantum 16.
template <int D, int BATCH>
__global__ __launch_bounds__(256) void k_agg(
    const ushort_t* __restrict__ h, const int* __restrict__ poffs,
    const int* __restrict__ deg, const int* __restrict__ csr2,
    int N, ushort_t* __restrict__ mean) {
    constexpr int LPR = D / 8;        // lanes per row
    constexpr int EPG = 64 / LPR;     // edges per gather
    constexpr int STEP = BATCH * EPG; // edges per iteration (== 16)
    constexpr int I4 = BATCH / 4;     // int4 index loads per lane
    int wid = (blockIdx.x * blockDim.x + threadIdx.x) >> 6;
    int lane = threadIdx.x & 63;
    if (wid >= N) return;
    const int seg = lane % LPR, sub = lane / LPR;
    int off = poffs[wid], cnt = deg[wid];
    int pcnt = (cnt + 15) & ~15;
    f32x2 acc[4] = {};
    const ushort_t* hp = h + seg * 8;
    int4 idxv[I4];
#pragma unroll
    for (int q = 0; q < I4; ++q)
        idxv[q] = *(const int4*)(csr2 + off + sub * BATCH + q * 4);
    for (int b = 0; b < pcnt; b += STEP) {
        uint4 d[BATCH];
#pragma unroll
        for (int u = 0; u < BATCH; ++u) {
            int id = ((const int*)idxv)[u];
            d[u] = *(const uint4*)(hp + (size_t)id * D);
        }
        int4 idxn[I4];
#pragma unroll
        for (int q = 0; q < I4; ++q)
            idxn[q] = *(const int4*)(csr2 + off + b + STEP + sub * BATCH + q * 4);
#pragma unroll
        for (int u = 0; u < BATCH; ++u) {
            uint32 dd[4] = {d[u].x, d[u].y, d[u].z, d[u].w};
#pragma unroll
            for (int p = 0; p < 4; ++p) {
                f32x2 tv;
                tv.x = asf(dd[p] << 16);
                tv.y = asf(dd[p] & 0xffff0000u);
                acc[p] += tv;
            }
        }
#pragma unroll
        for (int q = 0; q < I4; ++q) idxv[q] = idxn[q];
    }
    float a[8] = {acc[0].x, acc[0].y, acc[1].x, acc[1].y,
                  acc[2].x, acc[2].y, acc[3].x, acc[3].y};
#pragma unroll
    for (int o = LPR; o < 64; o <<= 1) {
#pragma unroll
        for (int k = 0; k < 8; ++k) a[k] += __shfl_xor(a[k], o);
    }
    if (sub == 0) {
        float inv = 1.f / fmaxf((float)cnt, 1.f);
        uint4 o4;
        o4.x = (uint32)f2bf(a[0] * inv) | ((uint32)f2bf(a[1] * inv) << 16);
        o4.y = (uint32)f2bf(a[2] * inv) | ((uint32)f2bf(a[3] * inv) << 16);
        o4.z = (uint32)f2bf(a[4] * inv) | ((uint32)f2bf(a[5] * inv) << 16);
        o4.w = (uint32)f2bf(a[6] * inv) | ((uint32)f2bf(a[7] * inv) << 16);
        *(uint4*)(mean + (size_t)wid * D + seg * 8) = o4;
    }
}

// ---------- B-stationary register GEMM ----------
// B panel (<=256 KB) lives in VGPRs: wave wv owns cols [wv*16*N_REP, +16*N_REP).
// A streamed: full-K rows staged to LDS (double-buffered), ONE barrier per tile.
// MODE 0: out = A1@B1^T + A2@B2^T, bf16 [M][256], BN stats in regs -> 2 atomics/lane.
// MODE 1: out = A1@B1^T; cols 0..63 -> bf16 t2 [M][64], 64..127 -> f32 r2 (+bias).
template <int KP, int MODE>
__global__ __launch_bounds__(512) void k_gemm2(
    const ushort_t* __restrict__ A1, const ushort_t* __restrict__ B1,
    const ushort_t* __restrict__ A2, const ushort_t* __restrict__ B2,
    const float* __restrict__ bias,
    ushort_t* __restrict__ out_bf, float* __restrict__ out_f,
    float* __restrict__ stats, int M, int nTiles) {
    constexpr int SIDES = (MODE == 0) ? 2 : 1;
    constexpr int N_REP = (MODE == 0) ? 2 : 1;
    constexpr int KCH = KP / 32;                       // MFMA k-chunks
    constexpr int JW = KP / 8;                         // 16B units per row
    constexpr int TILE = (MODE == 0 && KP == 256) ? 32 : 64;
    constexpr int M_REP = TILE / 16;
    constexpr int SLOTS = SIDES * TILE * JW;           // 16B slots per buffer
    __shared__ ushort_t Alds[2][SLOTS * 8];            // 2 x 32KB
    const int tid = threadIdx.x, lane = tid & 63, wv = tid >> 6;
    const int colBase = wv * (16 * N_REP) + (lane & 15);

    // B panel -> registers (L2-hot after first blocks)
    bf16x8 b[SIDES][KCH][N_REP];
#pragma unroll
    for (int s = 0; s < SIDES; ++s) {
        const ushort_t* B = s ? B2 : B1;
#pragma unroll
        for (int n = 0; n < N_REP; ++n)
#pragma unroll
            for (int c = 0; c < KCH; ++c)
                b[s][c][n] = *(const bf16x8*)&B[(size_t)(colBase + n * 16) * KP + c * 32 + (lane >> 4) * 8];
    }
    float bval = 0.f;
    if (MODE == 1) {
        int c2 = colBase - 64;
        bval = (c2 >= 0 && c2 < 47) ? bias[c2] : 0.f;
    }
    float ssum[N_REP] = {}, ssq[N_REP] = {};

    auto STAGE = [&](int t, int buf) {
        int r0 = t * TILE;
#pragma unroll
        for (int i = tid; i < SLOTS; i += 512) {
            int side = i / (TILE * JW);
            int rem = i - side * (TILE * JW);
            int r = rem / JW, j = rem - r * JW;
            int gr = min(r0 + r, M - 1);
            const ushort_t* Asrc = side ? A2 : A1;
            gload_lds16(Asrc + (size_t)gr * KP + j * 8, &Alds[buf][(size_t)i * 8]);
        }
    };

    int t0 = blockIdx.x;
    if (t0 < nTiles) STAGE(t0, 0);
    int buf = 0;
    for (int t = t0; t < nTiles; t += gridDim.x) {
        __syncthreads();                       // stage(buf) landed; prior reads done
        int tn = t + gridDim.x;
        if (tn < nTiles) STAGE(tn, buf ^ 1);   // async, hides under MFMA below
        f32x4 acc[M_REP][N_REP] = {};
#pragma unroll
        for (int s = 0; s < SIDES; ++s) {
            const ushort_t* base = &Alds[buf][s * TILE * JW * 8];
#pragma unroll
            for (int m = 0; m < M_REP; ++m) {
                bf16x8 a8[KCH];
#pragma unroll
                for (int c = 0; c < KCH; ++c)
                    a8[c] = *(const bf16x8*)&base[(m * 16 + (lane & 15)) * KP + c * 32 + (lane >> 4) * 8];
#pragma unroll
                for (int c = 0; c < KCH; ++c)
#pragma unroll
                    for (int n = 0; n < N_REP; ++n)
                        acc[m][n] = __builtin_amdgcn_mfma_f32_16x16x32_bf16(a8[c], b[s][c][n], acc[m][n], 0, 0, 0);
            }
        }
        int r0 = t * TILE;
#pragma unroll
        for (int n = 0; n < N_REP; ++n) {
            int col = colBase + n * 16;
#pragma unroll
            for (int m = 0; m < M_REP; ++m) {
#pragma unroll
                for (int r = 0; r < 4; ++r) {
                    int row = r0 + m * 16 + (lane >> 4) * 4 + r;
                    float v = acc[m][n][r];
                    if (row < M) {
                        if (MODE == 0) {
                            out_bf[(size_t)row * 256 + col] = f2bf(v);
                            ssum[n] += v;
                            ssq[n] += v * v;
                        } else {
                            if (col < 64) out_bf[(size_t)row * 64 + col] = f2bf(v);
                            else out_f[(size_t)row * 64 + (col - 64)] = v + bval;
                        }
                    }
                }
            }
        }
        buf ^= 1;
    }
    if (MODE == 0) {
#pragma unroll
        for (int n = 0; n < N_REP; ++n) {
            float s = ssum[n], q = ssq[n];
            s += __shfl_xor(s, 16); s += __shfl_xor(s, 32);
            q += __shfl_xor(q, 16); q += __shfl_xor(q, 32);
            if (lane < 16) {
                atomicAdd(&stats[colBase + n * 16], s);
                atomicAdd(&stats[256 + colBase + n * 16], q);
            }
        }
    }
}

// ---------- BN apply + ReLU, bf16 in / bf16 out, 16B vectorized ----------
__global__ void k_bnrelu(const ushort_t* __restrict__ h, const float* __restrict__ stats,
                         const float* __restrict__ g, const float* __restrict__ be,
                         int M, ushort_t* __restrict__ out) {
    int t = threadIdx.x;
    int cg = (t & 31) * 8;  // 8 cols per thread, 32 threads per row
    float invM = 1.f / (float)M;
    float sc[8], sh[8];
#pragma unroll
    for (int u = 0; u < 8; ++u) {
        int c = cg + u;
        float mean = stats[c] * invM;
        float var = stats[256 + c] * invM - mean * mean;
        float s = g[c] * rsqrtf(var + 1e-5f);
        sc[u] = s;
        sh[u] = be[c] - mean * s;
    }
    for (int r = blockIdx.x * 8 + (t >> 5); r < M; r += gridDim.x * 8) {
        uint4 d = *(const uint4*)(h + (size_t)r * 256 + cg);
        uint32 dd[4] = {d.x, d.y, d.z, d.w};
        uint32 w[4];
#pragma unroll
        for (int p = 0; p < 4; ++p) {
            float lo = bf2f((ushort_t)(dd[p] & 0xffff)) * sc[2 * p] + sh[2 * p];
            float hi = bf2f((ushort_t)(dd[p] >> 16)) * sc[2 * p + 1] + sh[2 * p + 1];
            w[p] = (uint32)f2bf(fmaxf(lo, 0.f)) | ((uint32)f2bf(fmaxf(hi, 0.f)) << 16);
        }
        uint4 o = {w[0], w[1], w[2], w[3]};
        *(uint4*)(out + (size_t)r * 256 + cg) = o;
    }
}

// ---------- layer 2: aggregate 64-dim transformed feats + log_softmax ----------
__global__ void k_agg_lsm(const ushort_t* __restrict__ t2, const float* __restrict__ r2,
                          const int* __restrict__ poffs, const int* __restrict__ deg,
                          const int* __restrict__ csr2, int N, float* __restrict__ out) {
    int wid = (blockIdx.x * blockDim.x + threadIdx.x) >> 6;
    int lane = threadIdx.x & 63;
    if (wid >= N) return;
    const int seg = lane & 7, sub = lane >> 3;
    int off = poffs[wid], cnt = deg[wid];
    int pcnt = (cnt + 15) & ~15;
    f32x2 acc[4] = {};
    const ushort_t* tp = t2 + seg * 8;
    int2 idx = *(const int2*)(csr2 + off + sub * 2);
    for (int b = 0; b < pcnt; b += 16) {
        uint4 d0 = *(const uint4*)(tp + (size_t)idx.x * 64);
        uint4 d1 = *(const uint4*)(tp + (size_t)idx.y * 64);
        int2 idxn = *(const int2*)(csr2 + off + b + 16 + sub * 2);
        uint32 dd[8] = {d0.x, d0.y, d0.z, d0.w, d1.x, d1.y, d1.z, d1.w};
#pragma unroll
        for (int q = 0; q < 8; ++q) {
            f32x2 tv;
            tv.x = asf(dd[q] << 16);
            tv.y = asf(dd[q] & 0xffff0000u);
            acc[q & 3] += tv;
        }
        idx = idxn;
    }
    float a[8] = {acc[0].x, acc[0].y, acc[1].x, acc[1].y,
                  acc[2].x, acc[2].y, acc[3].x, acc[3].y};
#pragma unroll
    for (int o = 8; o < 64; o <<= 1) {
#pragma unroll
        for (int k = 0; k < 8; ++k) a[k] += __shfl_xor(a[k], o);
    }
    if (sub == 0) {  // lanes 0..7 hold the full 64-dim row, 8 dims each
        float inv = 1.f / fmaxf((float)cnt, 1.f);
        float v[8];
#pragma unroll
        for (int k = 0; k < 8; ++k) {
            int c = seg * 8 + k;
            v[k] = a[k] * inv + r2[(size_t)wid * 64 + c];
            if (c >= 47) v[k] = -1e30f;
        }
        float m = v[0];
#pragma unroll
        for (int k = 1; k < 8; ++k) m = fmaxf(m, v[k]);
#pragma unroll
        for (int o = 1; o < 8; o <<= 1) m = fmaxf(m, __shfl_xor(m, o));
        float s = 0.f;
#pragma unroll
        for (int k = 0; k < 8; ++k) s += expf(v[k] - m);
#pragma unroll
        for (int o = 1; o < 8; o <<= 1) s += __shfl_xor(s, o);
        float lse = m + logf(s);
#pragma unroll
        for (int k = 0; k < 8; ++k) {
            int c = seg * 8 + k;
            if (c < 47) out[(size_t)wid * 47 + c] = v[k] - lse;
        }
    }
}

extern "C" void kernel_launch(void* const* d_in, const int* in_sizes, int n_in,
                              void* d_out, int out_size, void* d_ws, size_t ws_size,
                              hipStream_t stream) {
    const float* x   = (const float*)d_in[0];
    const int*   ei  = (const int*)d_in[1];
    const float* wl0 = (const float*)d_in[2];
    const float* wr0 = (const float*)d_in[3];
    const float* g0  = (const float*)d_in[5];
    const float* be0 = (const float*)d_in[6];
    const float* wl1 = (const float*)d_in[7];
    const float* wr1 = (const float*)d_in[8];
    const float* g1  = (const float*)d_in[10];
    const float* be1 = (const float*)d_in[11];
    const float* wl2 = (const float*)d_in[12];
    const float* wr2 = (const float*)d_in[13];
    const float* b2  = (const float*)d_in[14];
    float* out = (float*)d_out;

    const int N = in_sizes[0] / 100;
    const int E = in_sizes[1] / 2;
    const int* src = ei;
    const int* dst = ei + E;

    // workspace carve (256B aligned)
    char* p = (char*)d_ws;
    auto alloc = [&](size_t bytes) -> char* {
        char* r = p;
        p += (bytes + 255) & ~(size_t)255;
        return r;
    };
    const int NBLK = 128;
    const int nbins = (N + 1023) >> 10;           // 98 for N=100000
    const int scanN = nbins * NBLK;
    const size_t csr2N = (size_t)E + (size_t)nbins * 15376 + 64;
    ushort_t* xb   = (ushort_t*)alloc(((size_t)N + 1) * 128 * 2);   // +1 zero row
    ushort_t* hbuf = (ushort_t*)alloc(((size_t)N + 1) * 256 * 2);   // +1 zero row
    ushort_t* meanB = (ushort_t*)alloc(((size_t)N + 1) * 256 * 2);
    ushort_t* hpre = (ushort_t*)alloc((size_t)N * 256 * 2);
    int* deg   = (int*)alloc((size_t)N * 4);
    int* poffs = (int*)alloc((size_t)N * 4);
    int* csr2  = (int*)alloc(csr2N * 4);
    int* ebin  = (int*)alloc((size_t)E * 4);
    int* binCnt = (int*)alloc((size_t)scanN * 4);
    int* binOff = (int*)alloc((size_t)scanN * 4);
    float* stats0 = (float*)alloc(512 * 4);
    float* stats1 = (float*)alloc(512 * 4);
    ushort_t* wlt0 = (ushort_t*)alloc(256 * 128 * 2);
    ushort_t* wrt0 = (ushort_t*)alloc(256 * 128 * 2);
    ushort_t* wlt1 = (ushort_t*)alloc(256 * 256 * 2);
    ushort_t* wrt1 = (ushort_t*)alloc(256 * 256 * 2);
    ushort_t* wcat2 = (ushort_t*)alloc(128 * 256 * 2);
    if ((size_t)(p - (char*)d_ws) > ws_size) return;  // insufficient scratch

    // layer-2 buffers alias meanB (dead after layer-1 GEMM); t2 has N+1 rows
    ushort_t* t2 = meanB;                                   // [N+1][64] bf16
    float*    r2 = (float*)(meanB + ((size_t)N + 1) * 64);  // [N][64] f32

    k_cast_x<<<2048, 256, 0, stream>>>(x, xb, N, stats0, stats1,
                                       xb + (size_t)N * 128, hbuf + (size_t)N * 256);
    k_cast_wall<<<896, 256, 0, stream>>>(wl0, wr0, wl1, wr1, wl2, wr2,
                                         wlt0, wrt0, wlt1, wrt1, wcat2);

    // ---- CSR build (binned counting sort, padded) ----
    const int CH = (E + NBLK - 1) / NBLK;
    k_bincount<<<NBLK, 256, 0, stream>>>(dst, E, CH, nbins, NBLK, binCnt);
    k_scan_all<<<1, 1024, 0, stream>>>(binCnt, scanN, binOff);
    k_binscatter<<<NBLK, 256, 0, stream>>>(src, dst, E, CH, nbins, NBLK, binOff, ebin);
    k_bincsr<<<nbins, 1024, 0, stream>>>(ebin, binOff, E, N, nbins, NBLK, poffs, deg, csr2);

    int aggBlocks = (N + 3) / 4;      // 4 waves (nodes) per 256-thread block
    int tiles64 = (N + 63) / 64;
    int tiles32 = (N + 31) / 32;

    // ---- layer 0 ----
    k_agg<128, 4><<<aggBlocks, 256, 0, stream>>>(xb, poffs, deg, csr2, N, meanB);
    k_gemm2<128, 0><<<256, 512, 0, stream>>>(
        meanB, wlt0, xb, wrt0, nullptr, hpre, nullptr, stats0, N, tiles64);
    k_bnrelu<<<2048, 256, 0, stream>>>(hpre, stats0, g0, be0, N, hbuf);

    // ---- layer 1 ----
    k_agg<256, 8><<<aggBlocks, 256, 0, stream>>>(hbuf, poffs, deg, csr2, N, meanB);
    k_gemm2<256, 0><<<256, 512, 0, stream>>>(
        meanB, wlt1, hbuf, wrt1, nullptr, hpre, nullptr, stats1, N, tiles32);
    k_bnrelu<<<2048, 256, 0, stream>>>(hpre, stats1, g1, be1, N, hbuf);

    // ---- layer 2 (transform-first: mean(h)@wl2 == mean(h@wl2)) ----
    hipMemsetAsync(t2 + (size_t)N * 64, 0, 64 * 2, stream);  // zero row for padding
    k_gemm2<256, 1><<<512, 512, 0, stream>>>(
        hbuf, wcat2, nullptr, nullptr, b2, t2, r2, nullptr, N, tiles64);
    k_agg_lsm<<<(N + 3) / 4, 256, 0, stream>>>(t2, r2, poffs, deg, csr2, N, out);
}

// Round 12
// 514.867 us; speedup vs baseline: 1.0919x; 1.0374x over previous
//
#include <hip/hip_runtime.h>
#include <hip/hip_bf16.h>
#include <math.h>

#define DEVFN __device__ __forceinline__

typedef unsigned int uint32;
typedef unsigned short ushort_t;

using bf16x8 = __attribute__((ext_vector_type(8))) short;
using f32x4  = __attribute__((ext_vector_type(4))) float;
using f32x2  = __attribute__((ext_vector_type(2))) float;

DEVFN float bf2f(ushort_t u) {
    union { uint32 i; float f; } v; v.i = ((uint32)u) << 16; return v.f;
}
DEVFN float asf(uint32 u) {
    union { uint32 i; float f; } v; v.i = u; return v.f;
}
DEVFN ushort_t f2bf(float f) {
    union { float f; uint32 i; } v; v.f = f;
    uint32 u = v.i;
    uint32 r = (u + 0x7FFFu + ((u >> 16) & 1u)) >> 16;
    return (ushort_t)r;
}

DEVFN void gload_lds16(const void* g, void* l) {
    __builtin_amdgcn_global_load_lds(
        (const __attribute__((address_space(1))) void*)g,
        (__attribute__((address_space(3))) void*)l, 16, 0, 0);
}

// ---------- prep: zero scratch + cast x + all weight transposes (one kernel) ----------
DEVFN void cast_one(const float* __restrict__ w, ushort_t* __restrict__ wt,
                    int j, int K, int Nout, int Kp) {
    int k = j % Kp, n = j / Kp;
    float v = (k < K && n < Nout) ? w[k * Nout + n] : 0.f;
    wt[j] = f2bf(v);
}

__global__ void k_prep(const float* __restrict__ x, ushort_t* __restrict__ xb, int N,
                       float* __restrict__ stats0, float* __restrict__ stats1,
                       ushort_t* __restrict__ xrow, ushort_t* __restrict__ hrow,
                       const float* __restrict__ wl0, const float* __restrict__ wr0,
                       const float* __restrict__ wl1, const float* __restrict__ wr1,
                       const float* __restrict__ wl2, const float* __restrict__ wr2,
                       ushort_t* __restrict__ wlt0, ushort_t* __restrict__ wrt0,
                       ushort_t* __restrict__ wlt1, ushort_t* __restrict__ wrt1,
                       ushort_t* __restrict__ wcat2) {
    if (blockIdx.x == 0) {
        for (int t = threadIdx.x; t < 512; t += blockDim.x) {
            stats0[t] = 0.f;
            stats1[t] = 0.f;
        }
        for (int t = threadIdx.x; t < 128; t += blockDim.x) xrow[t] = 0;
        for (int t = threadIdx.x; t < 256; t += blockDim.x) hrow[t] = 0;
    }
    const int totalX = N * 128;
    const int totalW = 229376;
    for (int i = blockIdx.x * blockDim.x + threadIdx.x; i < totalX + totalW;
         i += gridDim.x * blockDim.x) {
        if (i < totalX) {
            int col = i & 127, row = i >> 7;
            float v = (col < 100) ? x[row * 100 + col] : 0.f;
            xb[i] = f2bf(v);
        } else {
            int j = i - totalX;
            if (j < 32768)        cast_one(wl0, wlt0, j, 100, 256, 128);
            else if (j < 65536)   cast_one(wr0, wrt0, j - 32768, 100, 256, 128);
            else if (j < 131072)  cast_one(wl1, wlt1, j - 65536, 256, 256, 256);
            else if (j < 196608)  cast_one(wr1, wrt1, j - 131072, 256, 256, 256);
            else if (j < 212992)  cast_one(wl2, wcat2, j - 196608, 256, 47, 256);
            else                  cast_one(wr2, wcat2 + 16384, j - 212992, 256, 47, 256);
        }
    }
}

// ---------- CSR build: binned counting sort by dst>>10, PADDED to 16 ----------
// NBLK=256 blocks: halves per-block LDS-atomic contention depth vs 128.
__global__ void k_bincount(const int* __restrict__ dst, int E, int CH, int nbins, int nblk,
                           int* __restrict__ binCnt) {
    __shared__ int scnt[128];
    int blk = blockIdx.x, tid = threadIdx.x;
    for (int b = tid; b < 128; b += 256) scnt[b] = 0;
    __syncthreads();
    int e0 = blk * CH, e1 = min(E, e0 + CH);
    for (int i = e0 + tid; i < e1; i += 256)
        atomicAdd(&scnt[dst[i] >> 10], 1);
    __syncthreads();
    for (int b = tid; b < nbins; b += 256) binCnt[b * nblk + blk] = scnt[b];
}

// single-block exclusive scan over n <= 32768 entries (PER=32 per thread)
__global__ void k_scan_all(const int* __restrict__ v, int n, int* __restrict__ outOff) {
    __shared__ int s[1024];
    int t = threadIdx.x;
    int b0 = t * 32;
    int loc[32];
    int sum = 0;
#pragma unroll
    for (int k = 0; k < 32; ++k) {
        int x = (b0 + k < n) ? v[b0 + k] : 0;
        loc[k] = x;
        sum += x;
    }
    s[t] = sum;
    __syncthreads();
    for (int o = 1; o < 1024; o <<= 1) {
        int add = (t >= o) ? s[t - o] : 0;
        __syncthreads();
        s[t] += add;
        __syncthreads();
    }
    int run = s[t] - sum;   // exclusive prefix of this thread's chunk
#pragma unroll
    for (int k = 0; k < 32; ++k) {
        if (b0 + k < n) outOff[b0 + k] = run;
        run += loc[k];
    }
}

__global__ void k_binscatter(const int* __restrict__ src, const int* __restrict__ dst,
                             int E, int CH, int nbins, int nblk,
                             const int* __restrict__ binOff, int* __restrict__ ebin) {
    __shared__ int scur[128];
    int blk = blockIdx.x, tid = threadIdx.x;
    for (int b = tid; b < nbins; b += 256) scur[b] = binOff[b * nblk + blk];
    __syncthreads();
    int e0 = blk * CH, e1 = min(E, e0 + CH);
    for (int i = e0 + tid; i < e1; i += 256) {
        int d = dst[i];
        int b = d >> 10;
        int pos = atomicAdd(&scur[b], 1);
        ebin[pos] = (src[i] << 10) | (d & 1023);
    }
}

// Per-bin CSR finalize with per-node padding to multiple of 16.
// Pad entries point to node N (a zeroed feature row). Per-bin padded base:
// pbase = align16(binStart) + bin*15376 (>= sum of previous bins' padded sizes).
__global__ void k_bincsr(const int* __restrict__ ebin, const int* __restrict__ binOff,
                         int E, int N, int nbins, int nblk,
                         int* __restrict__ poffs, int* __restrict__ deg, int* __restrict__ csr2) {
    __shared__ int sdeg[1024];
    __shared__ int scur[1024];
    int bin = blockIdx.x, t = threadIdx.x;
    int binStart = binOff[bin * nblk];
    int binEnd = (bin + 1 < nbins) ? binOff[(bin + 1) * nblk] : E;
    int pbase = ((binStart + 15) & ~15) + bin * 15376;
    sdeg[t] = 0;
    __syncthreads();
    for (int i = binStart + t; i < binEnd; i += 1024)
        atomicAdd(&sdeg[ebin[i] & 1023], 1);
    __syncthreads();
    int v = sdeg[t];
    int pv = (v + 15) & ~15;
    sdeg[t] = pv;
    __syncthreads();
    for (int o = 1; o < 1024; o <<= 1) {
        int add = (t >= o) ? sdeg[t - o] : 0;
        __syncthreads();
        sdeg[t] += add;
        __syncthreads();
    }
    int pex = sdeg[t] - pv;
    int node = bin * 1024 + t;
    if (node < N) { poffs[node] = pbase + pex; deg[node] = v; }
    scur[t] = pex;
    __syncthreads();
    for (int i = binStart + t; i < binEnd; i += 1024) {
        int e = ebin[i];
        int slot = atomicAdd(&scur[e & 1023], 1);
        csr2[pbase + slot] = e >> 10;
    }
    for (int j = v; j < pv; ++j) csr2[pbase + pex + j] = N;  // padding -> zero row
}

// ---------- aggregation: wave per node, padded edge lists, no masks ----------
// BATCH uint4 gathers in flight; STEP = BATCH*EPG must equal the pad quantum 16.
template <int D, int BATCH>
__global__ __launch_bounds__(256) void k_agg(
    const ushort_t* __restrict__ h, const int* __restrict__ poffs,
    const int* __restrict__ deg, const int* __restrict__ csr2,
    int N, ushort_t* __restrict__ mean) {
    constexpr int LPR = D / 8;        // lanes per row
    constexpr int EPG = 64 / LPR;     // edges per gather
    constexpr int STEP = BATCH * EPG; // edges per iteration (== 16)
    constexpr int I4 = BATCH / 4;     // int4 index loads per lane
    int wid = (blockIdx.x * blockDim.x + threadIdx.x) >> 6;
    int lane = threadIdx.x & 63;
    if (wid >= N) return;
    const int seg = lane % LPR, sub = lane / LPR;
    int off = poffs[wid], cnt = deg[wid];
    int pcnt = (cnt + 15) & ~15;
    f32x2 acc[4] = {};
    const ushort_t* hp = h + seg * 8;
    int4 idxv[I4];
#pragma unroll
    for (int q = 0; q < I4; ++q)
        idxv[q] = *(const int4*)(csr2 + off + sub * BATCH + q * 4);
    for (int b = 0; b < pcnt; b += STEP) {
        uint4 d[BATCH];
#pragma unroll
        for (int u = 0; u < BATCH; ++u) {
            int id = ((const int*)idxv)[u];
            d[u] = *(const uint4*)(hp + (size_t)id * D);
        }
        int4 idxn[I4];
#pragma unroll
        for (int q = 0; q < I4; ++q)
            idxn[q] = *(const int4*)(csr2 + off + b + STEP + sub * BATCH + q * 4);
#pragma unroll
        for (int u = 0; u < BATCH; ++u) {
            uint32 dd[4] = {d[u].x, d[u].y, d[u].z, d[u].w};
#pragma unroll
            for (int p = 0; p < 4; ++p) {
                f32x2 tv;
                tv.x = asf(dd[p] << 16);
                tv.y = asf(dd[p] & 0xffff0000u);
                acc[p] += tv;
            }
        }
#pragma unroll
        for (int q = 0; q < I4; ++q) idxv[q] = idxn[q];
    }
    float a[8] = {acc[0].x, acc[0].y, acc[1].x, acc[1].y,
                  acc[2].x, acc[2].y, acc[3].x, acc[3].y};
#pragma unroll
    for (int o = LPR; o < 64; o <<= 1) {
#pragma unroll
        for (int k = 0; k < 8; ++k) a[k] += __shfl_xor(a[k], o);
    }
    if (sub == 0) {
        float inv = 1.f / fmaxf((float)cnt, 1.f);
        uint4 o4;
        o4.x = (uint32)f2bf(a[0] * inv) | ((uint32)f2bf(a[1] * inv) << 16);
        o4.y = (uint32)f2bf(a[2] * inv) | ((uint32)f2bf(a[3] * inv) << 16);
        o4.z = (uint32)f2bf(a[4] * inv) | ((uint32)f2bf(a[5] * inv) << 16);
        o4.w = (uint32)f2bf(a[6] * inv) | ((uint32)f2bf(a[7] * inv) << 16);
        *(uint4*)(mean + (size_t)wid * D + seg * 8) = o4;
    }
}

// ---------- B-stationary register GEMM ----------
// B panel (<=256 KB) lives in VGPRs: wave wv owns cols [wv*16*N_REP, +16*N_REP).
// A streamed: full-K rows staged to LDS (double-buffered), ONE barrier per tile.
// MODE 0: out = A1@B1^T + A2@B2^T, bf16 [M][256], BN stats in regs -> 2 atomics/lane.
// MODE 1: out = A1@B1^T; cols 0..63 -> bf16 t2 [M][64], 64..127 -> f32 r2 (+bias).
template <int KP, int MODE>
__global__ __launch_bounds__(512) void k_gemm2(
    const ushort_t* __restrict__ A1, const ushort_t* __restrict__ B1,
    const ushort_t* __restrict__ A2, const ushort_t* __restrict__ B2,
    const float* __restrict__ bias,
    ushort_t* __restrict__ out_bf, float* __restrict__ out_f,
    float* __restrict__ stats, int M, int nTiles) {
    constexpr int SIDES = (MODE == 0) ? 2 : 1;
    constexpr int N_REP = (MODE == 0) ? 2 : 1;
    constexpr int KCH = KP / 32;                       // MFMA k-chunks
    constexpr int JW = KP / 8;                         // 16B units per row
    constexpr int TILE = (MODE == 0 && KP == 256) ? 32 : 64;
    constexpr int M_REP = TILE / 16;
    constexpr int SLOTS = SIDES * TILE * JW;           // 16B slots per buffer
    __shared__ ushort_t Alds[2][SLOTS * 8];            // 2 x 32KB
    const int tid = threadIdx.x, lane = tid & 63, wv = tid >> 6;
    const int colBase = wv * (16 * N_REP) + (lane & 15);

    // B panel -> registers (L2-hot after first blocks)
    bf16x8 b[SIDES][KCH][N_REP];
#pragma unroll
    for (int s = 0; s < SIDES; ++s) {
        const ushort_t* B = s ? B2 : B1;
#pragma unroll
        for (int n = 0; n < N_REP; ++n)
#pragma unroll
            for (int c = 0; c < KCH; ++c)
                b[s][c][n] = *(const bf16x8*)&B[(size_t)(colBase + n * 16) * KP + c * 32 + (lane >> 4) * 8];
    }
    float bval = 0.f;
    if (MODE == 1) {
        int c2 = colBase - 64;
        bval = (c2 >= 0 && c2 < 47) ? bias[c2] : 0.f;
    }
    float ssum[N_REP] = {}, ssq[N_REP] = {};

    auto STAGE = [&](int t, int buf) {
        int r0 = t * TILE;
#pragma unroll
        for (int i = tid; i < SLOTS; i += 512) {
            int side = i / (TILE * JW);
            int rem = i - side * (TILE * JW);
            int r = rem / JW, j = rem - r * JW;
            int gr = min(r0 + r, M - 1);
            const ushort_t* Asrc = side ? A2 : A1;
            gload_lds16(Asrc + (size_t)gr * KP + j * 8, &Alds[buf][(size_t)i * 8]);
        }
    };

    int t0 = blockIdx.x;
    if (t0 < nTiles) STAGE(t0, 0);
    int buf = 0;
    for (int t = t0; t < nTiles; t += gridDim.x) {
        __syncthreads();                       // stage(buf) landed; prior reads done
        int tn = t + gridDim.x;
        if (tn < nTiles) STAGE(tn, buf ^ 1);   // async, hides under MFMA below
        f32x4 acc[M_REP][N_REP] = {};
#pragma unroll
        for (int s = 0; s < SIDES; ++s) {
            const ushort_t* base = &Alds[buf][s * TILE * JW * 8];
#pragma unroll
            for (int m = 0; m < M_REP; ++m) {
                bf16x8 a8[KCH];
#pragma unroll
                for (int c = 0; c < KCH; ++c)
                    a8[c] = *(const bf16x8*)&base[(m * 16 + (lane & 15)) * KP + c * 32 + (lane >> 4) * 8];
#pragma unroll
                for (int c = 0; c < KCH; ++c)
#pragma unroll
                    for (int n = 0; n < N_REP; ++n)
                        acc[m][n] = __builtin_amdgcn_mfma_f32_16x16x32_bf16(a8[c], b[s][c][n], acc[m][n], 0, 0, 0);
            }
        }
        int r0 = t * TILE;
#pragma unroll
        for (int n = 0; n < N_REP; ++n) {
            int col = colBase + n * 16;
#pragma unroll
            for (int m = 0; m < M_REP; ++m) {
#pragma unroll
                for (int r = 0; r < 4; ++r) {
                    int row = r0 + m * 16 + (lane >> 4) * 4 + r;
                    float v = acc[m][n][r];
                    if (row < M) {
                        if (MODE == 0) {
                            out_bf[(size_t)row * 256 + col] = f2bf(v);
                            ssum[n] += v;
                            ssq[n] += v * v;
                        } else {
                            if (col < 64) out_bf[(size_t)row * 64 + col] = f2bf(v);
                            else out_f[(size_t)row * 64 + (col - 64)] = v + bval;
                        }
                    }
                }
            }
        }
        buf ^= 1;
    }
    if (MODE == 0) {
#pragma unroll
        for (int n = 0; n < N_REP; ++n) {
            float s = ssum[n], q = ssq[n];
            s += __shfl_xor(s, 16); s += __shfl_xor(s, 32);
            q += __shfl_xor(q, 16); q += __shfl_xor(q, 32);
            if (lane < 16) {
                atomicAdd(&stats[colBase + n * 16], s);
                atomicAdd(&stats[256 + colBase + n * 16], q);
            }
        }
    }
}

// ---------- BN apply + ReLU, bf16 in / bf16 out, 16B vectorized ----------
__global__ void k_bnrelu(const ushort_t* __restrict__ h, const float* __restrict__ stats,
                         const float* __restrict__ g, const float* __restrict__ be,
                         int M, ushort_t* __restrict__ out) {
    int t = threadIdx.x;
    int cg = (t & 31) * 8;  // 8 cols per thread, 32 threads per row
    float invM = 1.f / (float)M;
    float sc[8], sh[8];
#pragma unroll
    for (int u = 0; u < 8; ++u) {
        int c = cg + u;
        float mean = stats[c] * invM;
        float var = stats[256 + c] * invM - mean * mean;
        float s = g[c] * rsqrtf(var + 1e-5f);
        sc[u] = s;
        sh[u] = be[c] - mean * s;
    }
    for (int r = blockIdx.x * 8 + (t >> 5); r < M; r += gridDim.x * 8) {
        uint4 d = *(const uint4*)(h + (size_t)r * 256 + cg);
        uint32 dd[4] = {d.x, d.y, d.z, d.w};
        uint32 w[4];
#pragma unroll
        for (int p = 0; p < 4; ++p) {
            float lo = bf2f((ushort_t)(dd[p] & 0xffff)) * sc[2 * p] + sh[2 * p];
            float hi = bf2f((ushort_t)(dd[p] >> 16)) * sc[2 * p + 1] + sh[2 * p + 1];
            w[p] = (uint32)f2bf(fmaxf(lo, 0.f)) | ((uint32)f2bf(fmaxf(hi, 0.f)) << 16);
        }
        uint4 o = {w[0], w[1], w[2], w[3]};
        *(uint4*)(out + (size_t)r * 256 + cg) = o;
    }
}

// ---------- layer 2: aggregate 64-dim transformed feats + log_softmax ----------
__global__ void k_agg_lsm(const ushort_t* __restrict__ t2, const float* __restrict__ r2,
                          const int* __restrict__ poffs, const int* __restrict__ deg,
                          const int* __restrict__ csr2, int N, float* __restrict__ out) {
    int wid = (blockIdx.x * blockDim.x + threadIdx.x) >> 6;
    int lane = threadIdx.x & 63;
    if (wid >= N) return;
    const int seg = lane & 7, sub = lane >> 3;
    int off = poffs[wid], cnt = deg[wid];
    int pcnt = (cnt + 15) & ~15;
    f32x2 acc[4] = {};
    const ushort_t* tp = t2 + seg * 8;
    int2 idx = *(const int2*)(csr2 + off + sub * 2);
    for (int b = 0; b < pcnt; b += 16) {
        uint4 d0 = *(const uint4*)(tp + (size_t)idx.x * 64);
        uint4 d1 = *(const uint4*)(tp + (size_t)idx.y * 64);
        int2 idxn = *(const int2*)(csr2 + off + b + 16 + sub * 2);
        uint32 dd[8] = {d0.x, d0.y, d0.z, d0.w, d1.x, d1.y, d1.z, d1.w};
#pragma unroll
        for (int q = 0; q < 8; ++q) {
            f32x2 tv;
            tv.x = asf(dd[q] << 16);
            tv.y = asf(dd[q] & 0xffff0000u);
            acc[q & 3] += tv;
        }
        idx = idxn;
    }
    float a[8] = {acc[0].x, acc[0].y, acc[1].x, acc[1].y,
                  acc[2].x, acc[2].y, acc[3].x, acc[3].y};
#pragma unroll
    for (int o = 8; o < 64; o <<= 1) {
#pragma unroll
        for (int k = 0; k < 8; ++k) a[k] += __shfl_xor(a[k], o);
    }
    if (sub == 0) {  // lanes 0..7 hold the full 64-dim row, 8 dims each
        float inv = 1.f / fmaxf((float)cnt, 1.f);
        float v[8];
#pragma unroll
        for (int k = 0; k < 8; ++k) {
            int c = seg * 8 + k;
            v[k] = a[k] * inv + r2[(size_t)wid * 64 + c];
            if (c >= 47) v[k] = -1e30f;
        }
        float m = v[0];
#pragma unroll
        for (int k = 1; k < 8; ++k) m = fmaxf(m, v[k]);
#pragma unroll
        for (int o = 1; o < 8; o <<= 1) m = fmaxf(m, __shfl_xor(m, o));
        float s = 0.f;
#pragma unroll
        for (int k = 0; k < 8; ++k) s += expf(v[k] - m);
#pragma unroll
        for (int o = 1; o < 8; o <<= 1) s += __shfl_xor(s, o);
        float lse = m + logf(s);
#pragma unroll
        for (int k = 0; k < 8; ++k) {
            int c = seg * 8 + k;
            if (c < 47) out[(size_t)wid * 47 + c] = v[k] - lse;
        }
    }
}

extern "C" void kernel_launch(void* const* d_in, const int* in_sizes, int n_in,
                              void* d_out, int out_size, void* d_ws, size_t ws_size,
                              hipStream_t stream) {
    const float* x   = (const float*)d_in[0];
    const int*   ei  = (const int*)d_in[1];
    const float* wl0 = (const float*)d_in[2];
    const float* wr0 = (const float*)d_in[3];
    const float* g0  = (const float*)d_in[5];
    const float* be0 = (const float*)d_in[6];
    const float* wl1 = (const float*)d_in[7];
    const float* wr1 = (const float*)d_in[8];
    const float* g1  = (const float*)d_in[10];
    const float* be1 = (const float*)d_in[11];
    const float* wl2 = (const float*)d_in[12];
    const float* wr2 = (const float*)d_in[13];
    const float* b2  = (const float*)d_in[14];
    float* out = (float*)d_out;

    const int N = in_sizes[0] / 100;
    const int E = in_sizes[1] / 2;
    const int* src = ei;
    const int* dst = ei + E;

    // workspace carve (256B aligned)
    char* p = (char*)d_ws;
    auto alloc = [&](size_t bytes) -> char* {
        char* r = p;
        p += (bytes + 255) & ~(size_t)255;
        return r;
    };
    const int NBLK = 256;
    const int nbins = (N + 1023) >> 10;           // 98 for N=100000
    const int scanN = nbins * NBLK;               // 25088 <= 32768 scan capacity
    const size_t csr2N = (size_t)E + (size_t)nbins * 15376 + 64;
    ushort_t* xb   = (ushort_t*)alloc(((size_t)N + 1) * 128 * 2);   // +1 zero row
    ushort_t* hbuf = (ushort_t*)alloc(((size_t)N + 1) * 256 * 2);   // +1 zero row
    ushort_t* meanB = (ushort_t*)alloc(((size_t)N + 1) * 256 * 2);
    ushort_t* hpre = (ushort_t*)alloc((size_t)N * 256 * 2);
    int* deg   = (int*)alloc((size_t)N * 4);
    int* poffs = (int*)alloc((size_t)N * 4);
    int* csr2  = (int*)alloc(csr2N * 4);
    int* ebin  = (int*)alloc((size_t)E * 4);
    int* binCnt = (int*)alloc((size_t)scanN * 4);
    int* binOff = (int*)alloc((size_t)scanN * 4);
    float* stats0 = (float*)alloc(512 * 4);
    float* stats1 = (float*)alloc(512 * 4);
    ushort_t* wlt0 = (ushort_t*)alloc(256 * 128 * 2);
    ushort_t* wrt0 = (ushort_t*)alloc(256 * 128 * 2);
    ushort_t* wlt1 = (ushort_t*)alloc(256 * 256 * 2);
    ushort_t* wrt1 = (ushort_t*)alloc(256 * 256 * 2);
    ushort_t* wcat2 = (ushort_t*)alloc(128 * 256 * 2);
    if ((size_t)(p - (char*)d_ws) > ws_size) return;  // insufficient scratch

    // layer-2 buffers alias meanB (dead after layer-1 GEMM); t2 has N+1 rows
    ushort_t* t2 = meanB;                                   // [N+1][64] bf16
    float*    r2 = (float*)(meanB + ((size_t)N + 1) * 64);  // [N][64] f32

    k_prep<<<2048, 256, 0, stream>>>(x, xb, N, stats0, stats1,
                                     xb + (size_t)N * 128, hbuf + (size_t)N * 256,
                                     wl0, wr0, wl1, wr1, wl2, wr2,
                                     wlt0, wrt0, wlt1, wrt1, wcat2);

    // ---- CSR build (binned counting sort, padded) ----
    const int CH = (E + NBLK - 1) / NBLK;
    k_bincount<<<NBLK, 256, 0, stream>>>(dst, E, CH, nbins, NBLK, binCnt);
    k_scan_all<<<1, 1024, 0, stream>>>(binCnt, scanN, binOff);
    k_binscatter<<<NBLK, 256, 0, stream>>>(src, dst, E, CH, nbins, NBLK, binOff, ebin);
    k_bincsr<<<nbins, 1024, 0, stream>>>(ebin, binOff, E, N, nbins, NBLK, poffs, deg, csr2);

    int aggBlocks = (N + 3) / 4;      // 4 waves (nodes) per 256-thread block
    int tiles64 = (N + 63) / 64;
    int tiles32 = (N + 31) / 32;

    // ---- layer 0 ----
    k_agg<128, 4><<<aggBlocks, 256, 0, stream>>>(xb, poffs, deg, csr2, N, meanB);
    k_gemm2<128, 0><<<256, 512, 0, stream>>>(
        meanB, wlt0, xb, wrt0, nullptr, hpre, nullptr, stats0, N, tiles64);
    k_bnrelu<<<2048, 256, 0, stream>>>(hpre, stats0, g0, be0, N, hbuf);

    // ---- layer 1 ----
    k_agg<256, 8><<<aggBlocks, 256, 0, stream>>>(hbuf, poffs, deg, csr2, N, meanB);
    k_gemm2<256, 0><<<256, 512, 0, stream>>>(
        meanB, wlt1, hbuf, wrt1, nullptr, hpre, nullptr, stats1, N, tiles32);
    k_bnrelu<<<2048, 256, 0, stream>>>(hpre, stats1, g1, be1, N, hbuf);

    // ---- layer 2 (transform-first: mean(h)@wl2 == mean(h@wl2)) ----
    hipMemsetAsync(t2 + (size_t)N * 64, 0, 64 * 2, stream);  // zero row for padding
    k_gemm2<256, 1><<<512, 512, 0, stream>>>(
        hbuf, wcat2, nullptr, nullptr, b2, t2, r2, nullptr, N, tiles64);
    k_agg_lsm<<<(N + 3) / 4, 256, 0, stream>>>(t2, r2, poffs, deg, csr2, N, out);
}